// Round 7
// baseline (974.888 us; speedup 1.0000x reference)
//
#include <hip/hip_runtime.h>
#include <math.h>

#define D 64
#define ED 16
#define NEG 0.2f
#define BN_EPS 1e-5f

// ---------------- CSR construction ----------------

__global__ void k_count(const int* __restrict__ dst, int* __restrict__ cnt,
                        float* __restrict__ stat, int e) {
    int i = blockIdx.x * blockDim.x + threadIdx.x;
    if (blockIdx.x == 0 && threadIdx.x < 256) stat[threadIdx.x] = 0.f;  // zero BN stat bufs
    if (i < e) atomicAdd(&cnt[dst[i]], 1);
}

__global__ void k_scan1(const int* __restrict__ cnt, int* __restrict__ off,
                        int* __restrict__ bsum, int n) {
    __shared__ int buf[1024];
    int i = blockIdx.x * 1024 + threadIdx.x;
    int v = (i < n) ? cnt[i] : 0;
    buf[threadIdx.x] = v;
    __syncthreads();
    for (int d = 1; d < 1024; d <<= 1) {
        int t = (threadIdx.x >= (unsigned)d) ? buf[threadIdx.x - d] : 0;
        __syncthreads();
        buf[threadIdx.x] += t;
        __syncthreads();
    }
    if (i < n) off[i + 1] = buf[threadIdx.x];
    if (threadIdx.x == 1023) bsum[blockIdx.x] = buf[1023];
    if (i == 0) off[0] = 0;
}

__global__ void k_scan2(int* __restrict__ bsum, int nb) {
    int l = threadIdx.x;
    int v = (l < nb) ? bsum[l] : 0;
    #pragma unroll
    for (int o = 1; o < 64; o <<= 1) {
        int t = __shfl_up(v, o, 64);
        if (l >= o) v += t;
    }
    int ex = __shfl_up(v, 1, 64);
    if (l == 0) ex = 0;
    if (l < nb) bsum[l] = ex;
}

__global__ void k_scan3(int* __restrict__ off, const int* __restrict__ bsum, int n) {
    int i = blockIdx.x * blockDim.x + threadIdx.x;
    if (i < n) off[i + 1] += bsum[i >> 10];
}

// edge-balanced wave partition: wbeg[w] = first node of wave w's contiguous range.
// weight(node) = deg + C (C models per-node fixed cost: merge + self-loop + write).
__global__ void k_part(const int* __restrict__ off, int* __restrict__ wbeg,
                       int n, int nw) {
    int w = blockIdx.x * blockDim.x + threadIdx.x;
    if (w > nw) return;
    const long long C = 6;
    long long total = (long long)off[n] + C * n;
    long long target = (total * w) / nw;
    int lo = 0, hi = n;
    while (lo < hi) {
        int mid = (lo + hi) >> 1;
        long long f = (long long)off[mid] + C * mid;
        if (f < target) lo = mid + 1; else hi = mid;
    }
    wbeg[w] = lo;
}

// scatter src index AND edge_attr row into CSR (dst-sorted) order
__global__ void k_scatter(const int* __restrict__ src, const int* __restrict__ dst,
                          const int* __restrict__ off, int* __restrict__ fill,
                          int* __restrict__ srcs, float4* __restrict__ eas4,
                          const float4* __restrict__ ea4, int e) {
    int i = blockIdx.x * blockDim.x + threadIdx.x;
    if (i < e) {
        int d = dst[i];
        int p = off[d] + atomicAdd(&fill[d], 1);
        srcs[p] = src[i];
        size_t qi = 4 * (size_t)i;
        int qp = 4 * p;
        float4 a0 = ea4[qi], a1 = ea4[qi + 1], a2 = ea4[qi + 2], a3 = ea4[qi + 3];
        eas4[qp] = a0; eas4[qp + 1] = a1; eas4[qp + 2] = a2; eas4[qp + 3] = a3;
    }
}

// ---------------- gemm: xl/xr = BN'(h) @ {Wl,Wr}; BN finalize folded in ----------------
// mode: 0 = plain, 1 = BN, 2 = BN+ELU. stat points at this layer's raw {sum[64],sq[64]}.
// Broadcast via per-wave LDS staging + wave-uniform ds_read_b128 (R4: kept, -96us).
// gemm_grid=512: 3-4 grid-stride iters/wave amortize the 128 per-wave weight loads
// (R6 cross-check: non-gat time 268 -> 238us). DEFAULT launch bounds (R2 lesson).

__global__ __launch_bounds__(256) void k_gemm(
        const float* __restrict__ h, const float* __restrict__ Wl,
        const float* __restrict__ Wr, float* __restrict__ xl,
        float* __restrict__ xr, const float* __restrict__ stat,
        const float* __restrict__ gamma, const float* __restrict__ beta,
        int mode, int n) {
    __shared__ float lh[4][512];            // 8 rows x 64 cols per wave
    int lane = threadIdx.x & 63;
    int w = threadIdx.x >> 6;
    float wl[D], wr[D];
    #pragma unroll
    for (int k = 0; k < D; ++k) { wl[k] = Wl[k * D + lane]; wr[k] = Wr[k * D + lane]; }
    // staging role: lane l stages row (l>>3), cols (l&7)*8 .. +7 (2 float4)
    int srow = lane >> 3, scol = (lane & 7) * 8;
    float scs[8], shs[8];
    #pragma unroll
    for (int j = 0; j < 8; ++j) { scs[j] = 1.f; shs[j] = 0.f; }
    if (mode) {
        #pragma unroll
        for (int j = 0; j < 8; ++j) {
            int c = scol + j;
            float s = stat[c], q = stat[64 + c];
            float mean = s / (float)n;
            float var  = q / (float)n - mean * mean;
            float scv = gamma[c] * rsqrtf(var + BN_EPS);
            scs[j] = scv; shs[j] = beta[c] - mean * scv;
        }
    }
    int wid = blockIdx.x * 4 + w;
    int nw  = gridDim.x * 4;
    for (int r0 = wid * 8; r0 < n; r0 += nw * 8) {
        int r = r0 + srow;
        float4 v0 = make_float4(0.f, 0.f, 0.f, 0.f);
        float4 v1 = make_float4(0.f, 0.f, 0.f, 0.f);
        if (r < n) {
            const float4* hp = (const float4*)(h + (size_t)r * D + scol);
            v0 = hp[0]; v1 = hp[1];
        }
        if (mode) {
            v0.x = v0.x * scs[0] + shs[0]; v0.y = v0.y * scs[1] + shs[1];
            v0.z = v0.z * scs[2] + shs[2]; v0.w = v0.w * scs[3] + shs[3];
            v1.x = v1.x * scs[4] + shs[4]; v1.y = v1.y * scs[5] + shs[5];
            v1.z = v1.z * scs[6] + shs[6]; v1.w = v1.w * scs[7] + shs[7];
            if (mode == 2) {
                v0.x = (v0.x > 0.f) ? v0.x : expm1f(v0.x);
                v0.y = (v0.y > 0.f) ? v0.y : expm1f(v0.y);
                v0.z = (v0.z > 0.f) ? v0.z : expm1f(v0.z);
                v0.w = (v0.w > 0.f) ? v0.w : expm1f(v0.w);
                v1.x = (v1.x > 0.f) ? v1.x : expm1f(v1.x);
                v1.y = (v1.y > 0.f) ? v1.y : expm1f(v1.y);
                v1.z = (v1.z > 0.f) ? v1.z : expm1f(v1.z);
                v1.w = (v1.w > 0.f) ? v1.w : expm1f(v1.w);
            }
        }
        float* lp = &lh[w][srow * 64 + scol];
        ((float4*)lp)[0] = v0; ((float4*)lp)[1] = v1;
        // same-wave LDS write->read is in-order; no barrier needed (per-wave region)
        #pragma unroll
        for (int rr = 0; rr < 8; rr += 2) {
            const float4* row0 = (const float4*)&lh[w][rr * 64];
            const float4* row1 = (const float4*)&lh[w][rr * 64 + 64];
            float a0 = 0.f, b0 = 0.f, a1 = 0.f, b1 = 0.f;
            #pragma unroll
            for (int kk = 0; kk < 16; ++kk) {
                float4 h0 = row0[kk];       // uniform address -> broadcast
                float4 h1 = row1[kk];
                a0 += h0.x*wl[4*kk] + h0.y*wl[4*kk+1] + h0.z*wl[4*kk+2] + h0.w*wl[4*kk+3];
                b0 += h0.x*wr[4*kk] + h0.y*wr[4*kk+1] + h0.z*wr[4*kk+2] + h0.w*wr[4*kk+3];
                a1 += h1.x*wl[4*kk] + h1.y*wl[4*kk+1] + h1.z*wl[4*kk+2] + h1.w*wl[4*kk+3];
                b1 += h1.x*wr[4*kk] + h1.y*wr[4*kk+1] + h1.z*wr[4*kk+2] + h1.w*wr[4*kk+3];
            }
            int rA = r0 + rr, rB = rA + 1;
            if (rA < n) { xl[(size_t)rA * D + lane] = a0; xr[(size_t)rA * D + lane] = b0; }
            if (rB < n) { xl[(size_t)rB * D + lane] = a1; xr[(size_t)rB * D + lane] = b1; }
        }
    }
}

// ---------------- fused GATv2 ----------------
// wave = contiguous, edge-balanced node range (wbeg); 16-lane group g = edge slot
// (4 edges/pack); lane owns 4 features. eas is pre-sorted edge_attr (CSR order).
// No online max (logits bounded; ratio identical to max-subtracted form).
// R6 lesson: the ea double-buffer prefetch is load-bearing ILP (removing it:
// 117->147us even with +1 wave/SIMD). This round: R5's pipelined loop + ONLY the
// register trims that don't touch the loop body (stat->LDS atomics, b4 per-node
// reload, readfirstlane wid). Grid is set adaptively from the occupancy API so
// blocks are always exactly co-resident regardless of where VGPR lands.

#define EEVB(eb, j0) { \
    float4 u0 = *(const float4*)(lwp + (j0 + 0) * 64); \
    float4 u1 = *(const float4*)(lwp + (j0 + 1) * 64); \
    float4 u2 = *(const float4*)(lwp + (j0 + 2) * 64); \
    float4 u3 = *(const float4*)(lwp + (j0 + 3) * 64); \
    eex += eb.x*u0.x + eb.y*u1.x + eb.z*u2.x + eb.w*u3.x; \
    eey += eb.x*u0.y + eb.y*u1.y + eb.z*u2.y + eb.w*u3.y; \
    eez += eb.x*u0.z + eb.y*u1.z + eb.z*u2.z + eb.w*u3.z; \
    eew += eb.x*u0.w + eb.y*u1.w + eb.z*u2.w + eb.w*u3.w; }

__global__ __launch_bounds__(256) void k_gat(
        const float4* __restrict__ xl4, const float4* __restrict__ xr4,
        const float4* __restrict__ eas4, const int* __restrict__ srcs,
        const int* __restrict__ off, const int* __restrict__ wbeg,
        const float4* __restrict__ We4, const float4* __restrict__ att4,
        const float4* __restrict__ bias4, float* __restrict__ out,
        float* __restrict__ stat, int n, int do_elu) {
    __shared__ float ls[128];
    __shared__ float lwe[1024];             // We [16][64] staged once per block
    if (threadIdx.x < 128) ls[threadIdx.x] = 0.f;
    ((float4*)lwe)[threadIdx.x] = We4[threadIdx.x];   // 256 thr x 16B = 4 KB
    __syncthreads();
    int lane = threadIdx.x & 63;
    int g = lane >> 4, c16 = lane & 15;
    const float* lwp = lwe + c16 * 4;       // this lane's 4 output cols
    float4 av = att4[c16];
    int wid = __builtin_amdgcn_readfirstlane(
        blockIdx.x * (blockDim.x >> 6) + (threadIdx.x >> 6));
    int ns = wbeg[wid], nt = wbeg[wid + 1];
    int beg = (ns < nt) ? off[ns] : 0;
    for (int i = ns; i < nt; ++i) {
        int end = off[i + 1];
        int deg = end - beg;
        float4 xrv = xr4[i * 16 + c16];
        float denom = 0.f;
        float ax = 0.f, ay = 0.f, az = 0.f, aw = 0.f;
        float ex = 0.f, ey = 0.f, ez = 0.f, ew = 0.f;
        if (deg > 0) {
            // prologue: pack @ beg (srcs + ea + X all prefetched one iteration ahead)
            int actc = (g < deg);
            int p = beg + (actc ? g : 0);
            int s0 = srcs[p];
            int q = 4 * p;
            float4 e0 = eas4[q], e1 = eas4[q + 1], e2 = eas4[q + 2], e3 = eas4[q + 3];
            float4 X = xl4[s0 * 16 + c16];
            for (int pos = beg; pos < end; pos += 4) {
                int posn = pos + 4;
                int remn = end - posn;
                int actn = (remn > 0) && (g < remn);
                int pn = (remn > 0) ? posn + (actn ? g : 0) : pos;
                int sn = srcs[pn];                      // issue next srcs
                int qn = 4 * pn;                        // issue next ea (independent)
                float4 ne0 = eas4[qn],     ne1 = eas4[qn + 1];
                float4 ne2 = eas4[qn + 2], ne3 = eas4[qn + 3];
                // eev for current pack from LDS-we (covers sn latency)
                float eex = 0.f, eey = 0.f, eez = 0.f, eew = 0.f;
                EEVB(e0, 0) EEVB(e1, 4) EEVB(e2, 8) EEVB(e3, 12)
                // next xl gather (sn arrived during eev)
                float4 xn = xl4[sn * 16 + c16];
                float mk = actc ? 1.f : 0.f;
                ex += mk * eex; ey += mk * eey; ez += mk * eez; ew += mk * eew;
                float mx = X.x + xrv.x + eex;
                float my = X.y + xrv.y + eey;
                float mz = X.z + xrv.z + eez;
                float mw = X.w + xrv.w + eew;
                float p0 = fmaxf(mx, NEG * mx) * av.x
                         + fmaxf(my, NEG * my) * av.y
                         + fmaxf(mz, NEG * mz) * av.z
                         + fmaxf(mw, NEG * mw) * av.w;
                #pragma unroll
                for (int o = 1; o <= 8; o <<= 1) p0 += __shfl_xor(p0, o, 64);
                float ev = mk * __expf(p0);
                denom += ev;
                ax += ev * X.x;
                ay += ev * X.y;
                az += ev * X.z;
                aw += ev * X.w;
                e0 = ne0; e1 = ne1; e2 = ne2; e3 = ne3; X = xn; actc = actn;
            }
        }
        // merge 4 per-group partials (plain sums — no max bookkeeping)
        #pragma unroll
        for (int o = 16; o <= 32; o <<= 1) {
            denom += __shfl_xor(denom, o, 64);
            ax += __shfl_xor(ax, o, 64);
            ay += __shfl_xor(ay, o, 64);
            az += __shfl_xor(az, o, 64);
            aw += __shfl_xor(aw, o, 64);
            ex += __shfl_xor(ex, o, 64);
            ey += __shfl_xor(ey, o, 64);
            ez += __shfl_xor(ez, o, 64);
            ew += __shfl_xor(ew, o, 64);
        }
        // self-loop (loop_attr@We == mean of incoming eev; 0 if deg==0)
        float inv = (deg > 0) ? 1.f / (float)deg : 0.f;
        float4 xli = xl4[i * 16 + c16];
        float mx = xli.x + xrv.x + ex * inv;
        float my = xli.y + xrv.y + ey * inv;
        float mz = xli.z + xrv.z + ez * inv;
        float mw = xli.w + xrv.w + ew * inv;
        float p0 = fmaxf(mx, NEG * mx) * av.x
                 + fmaxf(my, NEG * my) * av.y
                 + fmaxf(mz, NEG * mz) * av.z
                 + fmaxf(mw, NEG * mw) * av.w;
        #pragma unroll
        for (int o = 1; o <= 8; o <<= 1) p0 += __shfl_xor(p0, o, 64);
        float ev = __expf(p0);
        denom += ev;
        ax += ev * xli.x;
        ay += ev * xli.y;
        az += ev * xli.z;
        aw += ev * xli.w;
        float invd = 1.f / denom;
        float4 b4 = bias4[c16];             // per-node reload (L1-hit), not live in loop
        float ox = ax * invd + b4.x;
        float oy = ay * invd + b4.y;
        float oz = az * invd + b4.z;
        float ow = aw * invd + b4.w;
        if (do_elu) {
            ox = (ox > 0.f) ? ox : expm1f(ox);
            oy = (oy > 0.f) ? oy : expm1f(oy);
            oz = (oz > 0.f) ? oz : expm1f(oz);
            ow = (ow > 0.f) ? ow : expm1f(ow);
        }
        if (g == 0) {
            float4 o4; o4.x = ox; o4.y = oy; o4.z = oz; o4.w = ow;
            ((float4*)out)[i * 16 + c16] = o4;
            if (stat) {                     // per-node LDS atomics (frees 8 VGPRs)
                atomicAdd(&ls[c16 * 4 + 0], ox);
                atomicAdd(&ls[c16 * 4 + 1], oy);
                atomicAdd(&ls[c16 * 4 + 2], oz);
                atomicAdd(&ls[c16 * 4 + 3], ow);
                atomicAdd(&ls[64 + c16 * 4 + 0], ox * ox);
                atomicAdd(&ls[64 + c16 * 4 + 1], oy * oy);
                atomicAdd(&ls[64 + c16 * 4 + 2], oz * oz);
                atomicAdd(&ls[64 + c16 * 4 + 3], ow * ow);
            }
        }
        beg = end;
    }
    if (stat) {
        __syncthreads();
        if (threadIdx.x < 128) atomicAdd(&stat[threadIdx.x], ls[threadIdx.x]);
    }
}

// ---------------- launch ----------------

extern "C" void kernel_launch(void* const* d_in, const int* in_sizes, int n_in,
                              void* d_out, int out_size, void* d_ws, size_t ws_size,
                              hipStream_t stream) {
    const float* x     = (const float*)d_in[0];
    const int*   ei    = (const int*)d_in[1];
    const float* ea    = (const float*)d_in[2];
    const float* Wl    = (const float*)d_in[3];
    const float* Wr    = (const float*)d_in[4];
    const float* We    = (const float*)d_in[5];
    const float* att   = (const float*)d_in[6];
    const float* bias  = (const float*)d_in[7];
    const float* gamma = (const float*)d_in[8];
    const float* beta  = (const float*)d_in[9];
    float* out = (float*)d_out;

    int n = in_sizes[0] / D;
    int e = in_sizes[1] / 2;
    const int* src = ei;
    const int* dst = ei + e;
    int nb = (n + 1023) / 1024;

    float* xl   = (float*)d_ws;
    float* xr   = xl + (size_t)n * D;
    float* hbuf = xr + (size_t)n * D;
    float* stat = hbuf + (size_t)n * D;        // [2][128]: raw {sum,sq} per BN
    float* eas  = stat + 256;                   // [e][16] pre-sorted edge_attr
    int* cnt  = (int*)(eas + (size_t)e * ED);
    int* fill = cnt + n;                        // adjacent to cnt: one memset
    int* off  = fill + n;
    int* bsum = off + n + 1;
    int* srcs = bsum + 256;
    int* wbeg = srcs + e;                       // [nw+1] edge-balanced partition

    // adaptive grid: exactly co-resident blocks (256 CUs x maxb blocks/CU),
    // robust to wherever VGPR lands (R6 lesson: never guess residency).
    int maxb = 6;
    (void)hipOccupancyMaxActiveBlocksPerMultiprocessor(&maxb, k_gat, 256, 0);
    if (maxb < 1) maxb = 1;
    if (maxb > 8) maxb = 8;
    const int gat_grid = maxb * 256;
    const int nw = gat_grid * 4;                // waves in k_gat
    const int gemm_grid = 512;                  // 3-4 grid-stride iters/wave (R6 win)

    hipMemsetAsync(cnt, 0, (size_t)(2 * n) * sizeof(int), stream);
    k_count<<<(e + 255) / 256, 256, 0, stream>>>(dst, cnt, stat, e);
    k_scan1<<<nb, 1024, 0, stream>>>(cnt, off, bsum, n);
    k_scan2<<<1, 64, 0, stream>>>(bsum, nb);
    k_scan3<<<(n + 255) / 256, 256, 0, stream>>>(off, bsum, n);
    k_part<<<(nw + 1 + 255) / 256, 256, 0, stream>>>(off, wbeg, n, nw);
    k_scatter<<<(e + 255) / 256, 256, 0, stream>>>(src, dst, off, fill, srcs,
                                                   (float4*)eas, (const float4*)ea, e);

    // layer 0: conv -> ELU (in gat) -> BN0 stats (epilogue); BN0 apply folded into gemm1
    k_gemm<<<gemm_grid, 256, 0, stream>>>(x, Wl, Wr, xl, xr, stat, gamma, beta, 0, n);
    k_gat<<<gat_grid, 256, 0, stream>>>((const float4*)xl, (const float4*)xr,
                                        (const float4*)eas, srcs, off, wbeg,
                                        (const float4*)We, (const float4*)att,
                                        (const float4*)bias, hbuf, stat, n, 1);
    // layer 1: conv (BN0 folded) -> BN1 stats (epilogue); BN1+ELU folded into gemm2
    k_gemm<<<gemm_grid, 256, 0, stream>>>(hbuf, Wl + D * D, Wr + D * D, xl, xr,
                                          stat, gamma, beta, 1, n);
    k_gat<<<gat_grid, 256, 0, stream>>>((const float4*)xl, (const float4*)xr,
                                        (const float4*)eas, srcs, off, wbeg,
                                        (const float4*)(We + ED * D), (const float4*)(att + D),
                                        (const float4*)(bias + D), hbuf, stat + 128, n, 0);
    // layer 2: conv (BN1+ELU folded) -> out
    k_gemm<<<gemm_grid, 256, 0, stream>>>(hbuf, Wl + 2 * D * D, Wr + 2 * D * D, xl, xr,
                                          stat + 128, gamma + D, beta + D, 2, n);
    k_gat<<<gat_grid, 256, 0, stream>>>((const float4*)xl, (const float4*)xr,
                                        (const float4*)eas, srcs, off, wbeg,
                                        (const float4*)(We + 2 * ED * D), (const float4*)(att + 2 * D),
                                        (const float4*)(bias + 2 * D), out, (float*)nullptr, n, 0);
}

// Round 8
// 608.216 us; speedup vs baseline: 1.6029x; 1.6029x over previous
//
#include <hip/hip_runtime.h>
#include <math.h>

#define D 64
#define ED 16
#define NEG 0.2f
#define BN_EPS 1e-5f

// ---------------- CSR construction ----------------

__global__ void k_count(const int* __restrict__ dst, int* __restrict__ cnt,
                        float* __restrict__ stat, int e) {
    int i = blockIdx.x * blockDim.x + threadIdx.x;
    if (blockIdx.x == 0 && threadIdx.x < 256) stat[threadIdx.x] = 0.f;  // zero BN stat bufs
    if (i < e) atomicAdd(&cnt[dst[i]], 1);
}

__global__ void k_scan1(const int* __restrict__ cnt, int* __restrict__ off,
                        int* __restrict__ bsum, int n) {
    __shared__ int buf[1024];
    int i = blockIdx.x * 1024 + threadIdx.x;
    int v = (i < n) ? cnt[i] : 0;
    buf[threadIdx.x] = v;
    __syncthreads();
    for (int d = 1; d < 1024; d <<= 1) {
        int t = (threadIdx.x >= (unsigned)d) ? buf[threadIdx.x - d] : 0;
        __syncthreads();
        buf[threadIdx.x] += t;
        __syncthreads();
    }
    if (i < n) off[i + 1] = buf[threadIdx.x];
    if (threadIdx.x == 1023) bsum[blockIdx.x] = buf[1023];
    if (i == 0) off[0] = 0;
}

__global__ void k_scan2(int* __restrict__ bsum, int nb) {
    int l = threadIdx.x;
    int v = (l < nb) ? bsum[l] : 0;
    #pragma unroll
    for (int o = 1; o < 64; o <<= 1) {
        int t = __shfl_up(v, o, 64);
        if (l >= o) v += t;
    }
    int ex = __shfl_up(v, 1, 64);
    if (l == 0) ex = 0;
    if (l < nb) bsum[l] = ex;
}

__global__ void k_scan3(int* __restrict__ off, const int* __restrict__ bsum, int n) {
    int i = blockIdx.x * blockDim.x + threadIdx.x;
    if (i < n) off[i + 1] += bsum[i >> 10];
}

// edge-balanced wave partition: wbeg[w] = first node of wave w's contiguous range.
// weight(node) = deg + C (C models per-node fixed cost: merge + self-loop + write).
__global__ void k_part(const int* __restrict__ off, int* __restrict__ wbeg,
                       int n, int nw) {
    int w = blockIdx.x * blockDim.x + threadIdx.x;
    if (w > nw) return;
    const long long C = 6;
    long long total = (long long)off[n] + C * n;
    long long target = (total * w) / nw;
    int lo = 0, hi = n;
    while (lo < hi) {
        int mid = (lo + hi) >> 1;
        long long f = (long long)off[mid] + C * mid;
        if (f < target) lo = mid + 1; else hi = mid;
    }
    wbeg[w] = lo;
}

// scatter src index AND edge_attr row into CSR (dst-sorted) order
__global__ void k_scatter(const int* __restrict__ src, const int* __restrict__ dst,
                          const int* __restrict__ off, int* __restrict__ fill,
                          int* __restrict__ srcs, float4* __restrict__ eas4,
                          const float4* __restrict__ ea4, int e) {
    int i = blockIdx.x * blockDim.x + threadIdx.x;
    if (i < e) {
        int d = dst[i];
        int p = off[d] + atomicAdd(&fill[d], 1);
        srcs[p] = src[i];
        size_t qi = 4 * (size_t)i;
        int qp = 4 * p;
        float4 a0 = ea4[qi], a1 = ea4[qi + 1], a2 = ea4[qi + 2], a3 = ea4[qi + 3];
        eas4[qp] = a0; eas4[qp + 1] = a1; eas4[qp + 2] = a2; eas4[qp + 3] = a3;
    }
}

// ---------------- gemm: xl/xr = BN'(h) @ {Wl,Wr}; BN finalize folded in ----------------
// mode: 0 = plain, 1 = BN, 2 = BN+ELU. stat points at this layer's raw {sum[64],sq[64]}.
// Broadcast via per-wave LDS staging + wave-uniform ds_read_b128 (R4: kept, -96us).
// gemm_grid=512: 3-4 grid-stride iters/wave amortize the 128 per-wave weight loads
// (R6 cross-check: non-gat time 268 -> 238us). DEFAULT launch bounds (R2 lesson).

__global__ __launch_bounds__(256) void k_gemm(
        const float* __restrict__ h, const float* __restrict__ Wl,
        const float* __restrict__ Wr, float* __restrict__ xl,
        float* __restrict__ xr, const float* __restrict__ stat,
        const float* __restrict__ gamma, const float* __restrict__ beta,
        int mode, int n) {
    __shared__ float lh[4][512];            // 8 rows x 64 cols per wave
    int lane = threadIdx.x & 63;
    int w = threadIdx.x >> 6;
    float wl[D], wr[D];
    #pragma unroll
    for (int k = 0; k < D; ++k) { wl[k] = Wl[k * D + lane]; wr[k] = Wr[k * D + lane]; }
    // staging role: lane l stages row (l>>3), cols (l&7)*8 .. +7 (2 float4)
    int srow = lane >> 3, scol = (lane & 7) * 8;
    float scs[8], shs[8];
    #pragma unroll
    for (int j = 0; j < 8; ++j) { scs[j] = 1.f; shs[j] = 0.f; }
    if (mode) {
        #pragma unroll
        for (int j = 0; j < 8; ++j) {
            int c = scol + j;
            float s = stat[c], q = stat[64 + c];
            float mean = s / (float)n;
            float var  = q / (float)n - mean * mean;
            float scv = gamma[c] * rsqrtf(var + BN_EPS);
            scs[j] = scv; shs[j] = beta[c] - mean * scv;
        }
    }
    int wid = blockIdx.x * 4 + w;
    int nw  = gridDim.x * 4;
    for (int r0 = wid * 8; r0 < n; r0 += nw * 8) {
        int r = r0 + srow;
        float4 v0 = make_float4(0.f, 0.f, 0.f, 0.f);
        float4 v1 = make_float4(0.f, 0.f, 0.f, 0.f);
        if (r < n) {
            const float4* hp = (const float4*)(h + (size_t)r * D + scol);
            v0 = hp[0]; v1 = hp[1];
        }
        if (mode) {
            v0.x = v0.x * scs[0] + shs[0]; v0.y = v0.y * scs[1] + shs[1];
            v0.z = v0.z * scs[2] + shs[2]; v0.w = v0.w * scs[3] + shs[3];
            v1.x = v1.x * scs[4] + shs[4]; v1.y = v1.y * scs[5] + shs[5];
            v1.z = v1.z * scs[6] + shs[6]; v1.w = v1.w * scs[7] + shs[7];
            if (mode == 2) {
                v0.x = (v0.x > 0.f) ? v0.x : expm1f(v0.x);
                v0.y = (v0.y > 0.f) ? v0.y : expm1f(v0.y);
                v0.z = (v0.z > 0.f) ? v0.z : expm1f(v0.z);
                v0.w = (v0.w > 0.f) ? v0.w : expm1f(v0.w);
                v1.x = (v1.x > 0.f) ? v1.x : expm1f(v1.x);
                v1.y = (v1.y > 0.f) ? v1.y : expm1f(v1.y);
                v1.z = (v1.z > 0.f) ? v1.z : expm1f(v1.z);
                v1.w = (v1.w > 0.f) ? v1.w : expm1f(v1.w);
            }
        }
        float* lp = &lh[w][srow * 64 + scol];
        ((float4*)lp)[0] = v0; ((float4*)lp)[1] = v1;
        // same-wave LDS write->read is in-order; no barrier needed (per-wave region)
        #pragma unroll
        for (int rr = 0; rr < 8; rr += 2) {
            const float4* row0 = (const float4*)&lh[w][rr * 64];
            const float4* row1 = (const float4*)&lh[w][rr * 64 + 64];
            float a0 = 0.f, b0 = 0.f, a1 = 0.f, b1 = 0.f;
            #pragma unroll
            for (int kk = 0; kk < 16; ++kk) {
                float4 h0 = row0[kk];       // uniform address -> broadcast
                float4 h1 = row1[kk];
                a0 += h0.x*wl[4*kk] + h0.y*wl[4*kk+1] + h0.z*wl[4*kk+2] + h0.w*wl[4*kk+3];
                b0 += h0.x*wr[4*kk] + h0.y*wr[4*kk+1] + h0.z*wr[4*kk+2] + h0.w*wr[4*kk+3];
                a1 += h1.x*wl[4*kk] + h1.y*wl[4*kk+1] + h1.z*wl[4*kk+2] + h1.w*wl[4*kk+3];
                b1 += h1.x*wr[4*kk] + h1.y*wr[4*kk+1] + h1.z*wr[4*kk+2] + h1.w*wr[4*kk+3];
            }
            int rA = r0 + rr, rB = rA + 1;
            if (rA < n) { xl[(size_t)rA * D + lane] = a0; xr[(size_t)rA * D + lane] = b0; }
            if (rB < n) { xl[(size_t)rB * D + lane] = a1; xr[(size_t)rB * D + lane] = b1; }
        }
    }
}

// ---------------- fused GATv2 ----------------
// wave = contiguous, edge-balanced node range (wbeg); 16-lane group g = edge slot
// (4 edges/pack); lane owns 4 features. eas is pre-sorted edge_attr (CSR order).
// No online max (logits bounded; ratio identical to max-subtracted form).
// This is R5's kernel verbatim — the measured optimum of this structure:
//   80 VGPR / 6 waves/SIMD / 117.4us. A/B evidence:
//   - R6: removing ea prefetch (68 VGPR, 7w) -> 147us. Prefetch is load-bearing ILP.
//   - R7: LDS-stat-atomics + b4-reload + readfirstlane trims (68 VGPR, 7w) -> 123us.
//     Trims cost more than the 7th wave buys. Register stat accumulators kept.
// Launch config must be STATIC (R7: occupancy API in kernel_launch broke graph
// capture, +370us of host gaps). gat_grid=1536 = exactly co-resident at 80 VGPR.

#define EEVB(eb, j0) { \
    float4 u0 = *(const float4*)(lwp + (j0 + 0) * 64); \
    float4 u1 = *(const float4*)(lwp + (j0 + 1) * 64); \
    float4 u2 = *(const float4*)(lwp + (j0 + 2) * 64); \
    float4 u3 = *(const float4*)(lwp + (j0 + 3) * 64); \
    eex += eb.x*u0.x + eb.y*u1.x + eb.z*u2.x + eb.w*u3.x; \
    eey += eb.x*u0.y + eb.y*u1.y + eb.z*u2.y + eb.w*u3.y; \
    eez += eb.x*u0.z + eb.y*u1.z + eb.z*u2.z + eb.w*u3.z; \
    eew += eb.x*u0.w + eb.y*u1.w + eb.z*u2.w + eb.w*u3.w; }

__global__ __launch_bounds__(256) void k_gat(
        const float4* __restrict__ xl4, const float4* __restrict__ xr4,
        const float4* __restrict__ eas4, const int* __restrict__ srcs,
        const int* __restrict__ off, const int* __restrict__ wbeg,
        const float4* __restrict__ We4, const float4* __restrict__ att4,
        const float4* __restrict__ bias4, float* __restrict__ out,
        float* __restrict__ stat, int n, int do_elu) {
    __shared__ float ls[128];
    __shared__ float lwe[1024];             // We [16][64] staged once per block
    if (threadIdx.x < 128) ls[threadIdx.x] = 0.f;
    ((float4*)lwe)[threadIdx.x] = We4[threadIdx.x];   // 256 thr x 16B = 4 KB
    __syncthreads();
    int lane = threadIdx.x & 63;
    int g = lane >> 4, c16 = lane & 15;
    const float* lwp = lwe + c16 * 4;       // this lane's 4 output cols
    float4 av = att4[c16];
    float4 b4 = bias4[c16];
    int wid = blockIdx.x * (blockDim.x >> 6) + (threadIdx.x >> 6);
    int ns = wbeg[wid], nt = wbeg[wid + 1];
    float bsx = 0.f, bsy = 0.f, bsz = 0.f, bsw = 0.f;
    float bqx = 0.f, bqy = 0.f, bqz = 0.f, bqw = 0.f;
    int beg = (ns < nt) ? off[ns] : 0;
    for (int i = ns; i < nt; ++i) {
        int end = off[i + 1];
        int deg = end - beg;
        float4 xrv = xr4[i * 16 + c16];
        float denom = 0.f;
        float ax = 0.f, ay = 0.f, az = 0.f, aw = 0.f;
        float ex = 0.f, ey = 0.f, ez = 0.f, ew = 0.f;
        if (deg > 0) {
            // prologue: pack @ beg (srcs + ea + X all prefetched one iteration ahead)
            int actc = (g < deg);
            int p = beg + (actc ? g : 0);
            int s0 = srcs[p];
            int q = 4 * p;
            float4 e0 = eas4[q], e1 = eas4[q + 1], e2 = eas4[q + 2], e3 = eas4[q + 3];
            float4 X = xl4[s0 * 16 + c16];
            for (int pos = beg; pos < end; pos += 4) {
                int posn = pos + 4;
                int remn = end - posn;
                int actn = (remn > 0) && (g < remn);
                int pn = (remn > 0) ? posn + (actn ? g : 0) : pos;
                int sn = srcs[pn];                      // issue next srcs
                int qn = 4 * pn;                        // issue next ea (independent)
                float4 ne0 = eas4[qn],     ne1 = eas4[qn + 1];
                float4 ne2 = eas4[qn + 2], ne3 = eas4[qn + 3];
                // eev for current pack from LDS-we (covers sn latency)
                float eex = 0.f, eey = 0.f, eez = 0.f, eew = 0.f;
                EEVB(e0, 0) EEVB(e1, 4) EEVB(e2, 8) EEVB(e3, 12)
                // next xl gather (sn arrived during eev)
                float4 xn = xl4[sn * 16 + c16];
                float mk = actc ? 1.f : 0.f;
                ex += mk * eex; ey += mk * eey; ez += mk * eez; ew += mk * eew;
                float mx = X.x + xrv.x + eex;
                float my = X.y + xrv.y + eey;
                float mz = X.z + xrv.z + eez;
                float mw = X.w + xrv.w + eew;
                float p0 = fmaxf(mx, NEG * mx) * av.x
                         + fmaxf(my, NEG * my) * av.y
                         + fmaxf(mz, NEG * mz) * av.z
                         + fmaxf(mw, NEG * mw) * av.w;
                #pragma unroll
                for (int o = 1; o <= 8; o <<= 1) p0 += __shfl_xor(p0, o, 64);
                float ev = mk * __expf(p0);
                denom += ev;
                ax += ev * X.x;
                ay += ev * X.y;
                az += ev * X.z;
                aw += ev * X.w;
                e0 = ne0; e1 = ne1; e2 = ne2; e3 = ne3; X = xn; actc = actn;
            }
        }
        // merge 4 per-group partials (plain sums — no max bookkeeping)
        #pragma unroll
        for (int o = 16; o <= 32; o <<= 1) {
            denom += __shfl_xor(denom, o, 64);
            ax += __shfl_xor(ax, o, 64);
            ay += __shfl_xor(ay, o, 64);
            az += __shfl_xor(az, o, 64);
            aw += __shfl_xor(aw, o, 64);
            ex += __shfl_xor(ex, o, 64);
            ey += __shfl_xor(ey, o, 64);
            ez += __shfl_xor(ez, o, 64);
            ew += __shfl_xor(ew, o, 64);
        }
        // self-loop (loop_attr@We == mean of incoming eev; 0 if deg==0)
        float inv = (deg > 0) ? 1.f / (float)deg : 0.f;
        float4 xli = xl4[i * 16 + c16];
        float mx = xli.x + xrv.x + ex * inv;
        float my = xli.y + xrv.y + ey * inv;
        float mz = xli.z + xrv.z + ez * inv;
        float mw = xli.w + xrv.w + ew * inv;
        float p0 = fmaxf(mx, NEG * mx) * av.x
                 + fmaxf(my, NEG * my) * av.y
                 + fmaxf(mz, NEG * mz) * av.z
                 + fmaxf(mw, NEG * mw) * av.w;
        #pragma unroll
        for (int o = 1; o <= 8; o <<= 1) p0 += __shfl_xor(p0, o, 64);
        float ev = __expf(p0);
        denom += ev;
        ax += ev * xli.x;
        ay += ev * xli.y;
        az += ev * xli.z;
        aw += ev * xli.w;
        float invd = 1.f / denom;
        float ox = ax * invd + b4.x;
        float oy = ay * invd + b4.y;
        float oz = az * invd + b4.z;
        float ow = aw * invd + b4.w;
        if (do_elu) {
            ox = (ox > 0.f) ? ox : expm1f(ox);
            oy = (oy > 0.f) ? oy : expm1f(oy);
            oz = (oz > 0.f) ? oz : expm1f(oz);
            ow = (ow > 0.f) ? ow : expm1f(ow);
        }
        if (g == 0) {
            float4 o4; o4.x = ox; o4.y = oy; o4.z = oz; o4.w = ow;
            ((float4*)out)[i * 16 + c16] = o4;
            if (stat) {
                bsx += ox; bsy += oy; bsz += oz; bsw += ow;
                bqx += ox * ox; bqy += oy * oy; bqz += oz * oz; bqw += ow * ow;
            }
        }
        beg = end;
    }
    if (stat) {
        if (g == 0) {
            atomicAdd(&ls[c16 * 4 + 0], bsx);
            atomicAdd(&ls[c16 * 4 + 1], bsy);
            atomicAdd(&ls[c16 * 4 + 2], bsz);
            atomicAdd(&ls[c16 * 4 + 3], bsw);
            atomicAdd(&ls[64 + c16 * 4 + 0], bqx);
            atomicAdd(&ls[64 + c16 * 4 + 1], bqy);
            atomicAdd(&ls[64 + c16 * 4 + 2], bqz);
            atomicAdd(&ls[64 + c16 * 4 + 3], bqw);
        }
        __syncthreads();
        if (threadIdx.x < 128) atomicAdd(&stat[threadIdx.x], ls[threadIdx.x]);
    }
}

// ---------------- launch ----------------

extern "C" void kernel_launch(void* const* d_in, const int* in_sizes, int n_in,
                              void* d_out, int out_size, void* d_ws, size_t ws_size,
                              hipStream_t stream) {
    const float* x     = (const float*)d_in[0];
    const int*   ei    = (const int*)d_in[1];
    const float* ea    = (const float*)d_in[2];
    const float* Wl    = (const float*)d_in[3];
    const float* Wr    = (const float*)d_in[4];
    const float* We    = (const float*)d_in[5];
    const float* att   = (const float*)d_in[6];
    const float* bias  = (const float*)d_in[7];
    const float* gamma = (const float*)d_in[8];
    const float* beta  = (const float*)d_in[9];
    float* out = (float*)d_out;

    int n = in_sizes[0] / D;
    int e = in_sizes[1] / 2;
    const int* src = ei;
    const int* dst = ei + e;
    int nb = (n + 1023) / 1024;

    float* xl   = (float*)d_ws;
    float* xr   = xl + (size_t)n * D;
    float* hbuf = xr + (size_t)n * D;
    float* stat = hbuf + (size_t)n * D;        // [2][128]: raw {sum,sq} per BN
    float* eas  = stat + 256;                   // [e][16] pre-sorted edge_attr
    int* cnt  = (int*)(eas + (size_t)e * ED);
    int* fill = cnt + n;                        // adjacent to cnt: one memset
    int* off  = fill + n;
    int* bsum = off + n + 1;
    int* srcs = bsum + 256;
    int* wbeg = srcs + e;                       // [nw+1] edge-balanced partition

    // STATIC grids (R7 lesson: no runtime queries in kernel_launch).
    // k_gat VGPR=80 (R5 measured) -> 6 waves/SIMD -> 6 blocks/CU: 1536.
    const int gat_grid  = 1536;
    const int nw = gat_grid * 4;                // waves in k_gat
    const int gemm_grid = 512;                  // 3-4 grid-stride iters/wave (R6 win)

    hipMemsetAsync(cnt, 0, (size_t)(2 * n) * sizeof(int), stream);
    k_count<<<(e + 255) / 256, 256, 0, stream>>>(dst, cnt, stat, e);
    k_scan1<<<nb, 1024, 0, stream>>>(cnt, off, bsum, n);
    k_scan2<<<1, 64, 0, stream>>>(bsum, nb);
    k_scan3<<<(n + 255) / 256, 256, 0, stream>>>(off, bsum, n);
    k_part<<<(nw + 1 + 255) / 256, 256, 0, stream>>>(off, wbeg, n, nw);
    k_scatter<<<(e + 255) / 256, 256, 0, stream>>>(src, dst, off, fill, srcs,
                                                   (float4*)eas, (const float4*)ea, e);

    // layer 0: conv -> ELU (in gat) -> BN0 stats (epilogue); BN0 apply folded into gemm1
    k_gemm<<<gemm_grid, 256, 0, stream>>>(x, Wl, Wr, xl, xr, stat, gamma, beta, 0, n);
    k_gat<<<gat_grid, 256, 0, stream>>>((const float4*)xl, (const float4*)xr,
                                        (const float4*)eas, srcs, off, wbeg,
                                        (const float4*)We, (const float4*)att,
                                        (const float4*)bias, hbuf, stat, n, 1);
    // layer 1: conv (BN0 folded) -> BN1 stats (epilogue); BN1+ELU folded into gemm2
    k_gemm<<<gemm_grid, 256, 0, stream>>>(hbuf, Wl + D * D, Wr + D * D, xl, xr,
                                          stat, gamma, beta, 1, n);
    k_gat<<<gat_grid, 256, 0, stream>>>((const float4*)xl, (const float4*)xr,
                                        (const float4*)eas, srcs, off, wbeg,
                                        (const float4*)(We + ED * D), (const float4*)(att + D),
                                        (const float4*)(bias + D), hbuf, stat + 128, n, 0);
    // layer 2: conv (BN1+ELU folded) -> out
    k_gemm<<<gemm_grid, 256, 0, stream>>>(hbuf, Wl + 2 * D * D, Wr + 2 * D * D, xl, xr,
                                          stat + 128, gamma + D, beta + D, 2, n);
    k_gat<<<gat_grid, 256, 0, stream>>>((const float4*)xl, (const float4*)xr,
                                        (const float4*)eas, srcs, off, wbeg,
                                        (const float4*)(We + 2 * ED * D), (const float4*)(att + 2 * D),
                                        (const float4*)(bias + 2 * D), out, (float*)nullptr, n, 0);
}

// Round 9
// 599.891 us; speedup vs baseline: 1.6251x; 1.0139x over previous
//
#include <hip/hip_runtime.h>
#include <math.h>

#define D 64
#define ED 16
#define NEG 0.2f
#define BN_EPS 1e-5f

// ---------------- CSR construction ----------------

__global__ void k_count(const int* __restrict__ dst, int* __restrict__ cnt,
                        float* __restrict__ stat, int e) {
    int i = blockIdx.x * blockDim.x + threadIdx.x;
    if (blockIdx.x == 0 && threadIdx.x < 256) stat[threadIdx.x] = 0.f;  // zero BN stat bufs
    if (i < e) atomicAdd(&cnt[dst[i]], 1);
}

__global__ void k_scan1(const int* __restrict__ cnt, int* __restrict__ off,
                        int* __restrict__ bsum, int n) {
    __shared__ int buf[1024];
    int i = blockIdx.x * 1024 + threadIdx.x;
    int v = (i < n) ? cnt[i] : 0;
    buf[threadIdx.x] = v;
    __syncthreads();
    for (int d = 1; d < 1024; d <<= 1) {
        int t = (threadIdx.x >= (unsigned)d) ? buf[threadIdx.x - d] : 0;
        __syncthreads();
        buf[threadIdx.x] += t;
        __syncthreads();
    }
    if (i < n) off[i + 1] = buf[threadIdx.x];
    if (threadIdx.x == 1023) bsum[blockIdx.x] = buf[1023];
    if (i == 0) off[0] = 0;
}

__global__ void k_scan2(int* __restrict__ bsum, int nb) {
    int l = threadIdx.x;
    int v = (l < nb) ? bsum[l] : 0;
    #pragma unroll
    for (int o = 1; o < 64; o <<= 1) {
        int t = __shfl_up(v, o, 64);
        if (l >= o) v += t;
    }
    int ex = __shfl_up(v, 1, 64);
    if (l == 0) ex = 0;
    if (l < nb) bsum[l] = ex;
}

__global__ void k_scan3(int* __restrict__ off, const int* __restrict__ bsum, int n) {
    int i = blockIdx.x * blockDim.x + threadIdx.x;
    if (i < n) off[i + 1] += bsum[i >> 10];
}

// edge-balanced wave partition: wbeg[w] = first node of wave w's contiguous range.
// weight(node) = deg + C (C models per-node fixed cost: merge + self-loop + write).
__global__ void k_part(const int* __restrict__ off, int* __restrict__ wbeg,
                       int n, int nw) {
    int w = blockIdx.x * blockDim.x + threadIdx.x;
    if (w > nw) return;
    const long long C = 6;
    long long total = (long long)off[n] + C * n;
    long long target = (total * w) / nw;
    int lo = 0, hi = n;
    while (lo < hi) {
        int mid = (lo + hi) >> 1;
        long long f = (long long)off[mid] + C * mid;
        if (f < target) lo = mid + 1; else hi = mid;
    }
    wbeg[w] = lo;
}

// scatter src index AND edge_attr row into CSR (dst-sorted) order
__global__ void k_scatter(const int* __restrict__ src, const int* __restrict__ dst,
                          const int* __restrict__ off, int* __restrict__ fill,
                          int* __restrict__ srcs, float4* __restrict__ eas4,
                          const float4* __restrict__ ea4, int e) {
    int i = blockIdx.x * blockDim.x + threadIdx.x;
    if (i < e) {
        int d = dst[i];
        int p = off[d] + atomicAdd(&fill[d], 1);
        srcs[p] = src[i];
        size_t qi = 4 * (size_t)i;
        int qp = 4 * p;
        float4 a0 = ea4[qi], a1 = ea4[qi + 1], a2 = ea4[qi + 2], a3 = ea4[qi + 3];
        eas4[qp] = a0; eas4[qp + 1] = a1; eas4[qp + 2] = a2; eas4[qp + 3] = a3;
    }
}

// ---------------- gemm: xl/xr = BN'(h) @ {Wl,Wr}; BN finalize folded in ----------------
// mode: 0 = plain, 1 = BN, 2 = BN+ELU. stat points at this layer's raw {sum[64],sq[64]}.
// Broadcast via per-wave LDS staging + wave-uniform ds_read_b128 (R4: kept).
// R9: software double-buffer — next group's h loads issue BEFORE the current
// group's compute (2048 VALU cyc hides the ~500-900cy global latency); BN/ELU +
// ds_write of the arrived data AFTER compute. Same-wave DS ordering makes the
// single LDS buffer safe (compute reads precede writes in program order).
// At grid 512 (2 blocks/CU) the old version exposed full load latency per
// iteration with only 2 waves/SIMD of TLP. gemm_grid=512 kept (R6 win).
// DEFAULT launch bounds (R2 lesson: never cap a reg-heavy kernel).

#define BN_ELU_APPLY(v0, v1) { \
    if (mode) { \
        v0.x = v0.x * scs[0] + shs[0]; v0.y = v0.y * scs[1] + shs[1]; \
        v0.z = v0.z * scs[2] + shs[2]; v0.w = v0.w * scs[3] + shs[3]; \
        v1.x = v1.x * scs[4] + shs[4]; v1.y = v1.y * scs[5] + shs[5]; \
        v1.z = v1.z * scs[6] + shs[6]; v1.w = v1.w * scs[7] + shs[7]; \
        if (mode == 2) { \
            v0.x = (v0.x > 0.f) ? v0.x : expm1f(v0.x); \
            v0.y = (v0.y > 0.f) ? v0.y : expm1f(v0.y); \
            v0.z = (v0.z > 0.f) ? v0.z : expm1f(v0.z); \
            v0.w = (v0.w > 0.f) ? v0.w : expm1f(v0.w); \
            v1.x = (v1.x > 0.f) ? v1.x : expm1f(v1.x); \
            v1.y = (v1.y > 0.f) ? v1.y : expm1f(v1.y); \
            v1.z = (v1.z > 0.f) ? v1.z : expm1f(v1.z); \
            v1.w = (v1.w > 0.f) ? v1.w : expm1f(v1.w); \
        } \
    } }

__global__ __launch_bounds__(256) void k_gemm(
        const float* __restrict__ h, const float* __restrict__ Wl,
        const float* __restrict__ Wr, float* __restrict__ xl,
        float* __restrict__ xr, const float* __restrict__ stat,
        const float* __restrict__ gamma, const float* __restrict__ beta,
        int mode, int n) {
    __shared__ float lh[4][512];            // 8 rows x 64 cols per wave
    int lane = threadIdx.x & 63;
    int w = threadIdx.x >> 6;
    float wl[D], wr[D];
    #pragma unroll
    for (int k = 0; k < D; ++k) { wl[k] = Wl[k * D + lane]; wr[k] = Wr[k * D + lane]; }
    // staging role: lane l stages row (l>>3), cols (l&7)*8 .. +7 (2 float4)
    int srow = lane >> 3, scol = (lane & 7) * 8;
    float scs[8], shs[8];
    #pragma unroll
    for (int j = 0; j < 8; ++j) { scs[j] = 1.f; shs[j] = 0.f; }
    if (mode) {
        #pragma unroll
        for (int j = 0; j < 8; ++j) {
            int c = scol + j;
            float s = stat[c], q = stat[64 + c];
            float mean = s / (float)n;
            float var  = q / (float)n - mean * mean;
            float scv = gamma[c] * rsqrtf(var + BN_EPS);
            scs[j] = scv; shs[j] = beta[c] - mean * scv;
        }
    }
    int wid = blockIdx.x * 4 + w;
    int stride = gridDim.x * 4 * 8;
    int r0 = wid * 8;
    float* lp = &lh[w][srow * 64 + scol];
    if (r0 < n) {
        // prologue: stage group r0
        int r = r0 + srow;
        float4 v0 = make_float4(0.f, 0.f, 0.f, 0.f);
        float4 v1 = make_float4(0.f, 0.f, 0.f, 0.f);
        if (r < n) {
            const float4* hp = (const float4*)(h + (size_t)r * D + scol);
            v0 = hp[0]; v1 = hp[1];
        }
        BN_ELU_APPLY(v0, v1)
        ((float4*)lp)[0] = v0; ((float4*)lp)[1] = v1;
    }
    for (; r0 < n; r0 += stride) {
        int rn = r0 + stride;
        // issue next group's loads FIRST (latency hides under this group's compute)
        float4 p0 = make_float4(0.f, 0.f, 0.f, 0.f);
        float4 p1 = make_float4(0.f, 0.f, 0.f, 0.f);
        if (rn < n) {
            int r = rn + srow;
            if (r < n) {
                const float4* hp = (const float4*)(h + (size_t)r * D + scol);
                p0 = hp[0]; p1 = hp[1];
            }
        }
        // compute current group from LDS (same-wave write->read is in-order)
        #pragma unroll
        for (int rr = 0; rr < 8; rr += 2) {
            const float4* row0 = (const float4*)&lh[w][rr * 64];
            const float4* row1 = (const float4*)&lh[w][rr * 64 + 64];
            float a0 = 0.f, b0 = 0.f, a1 = 0.f, b1 = 0.f;
            #pragma unroll
            for (int kk = 0; kk < 16; ++kk) {
                float4 h0 = row0[kk];       // uniform address -> broadcast
                float4 h1 = row1[kk];
                a0 += h0.x*wl[4*kk] + h0.y*wl[4*kk+1] + h0.z*wl[4*kk+2] + h0.w*wl[4*kk+3];
                b0 += h0.x*wr[4*kk] + h0.y*wr[4*kk+1] + h0.z*wr[4*kk+2] + h0.w*wr[4*kk+3];
                a1 += h1.x*wl[4*kk] + h1.y*wl[4*kk+1] + h1.z*wl[4*kk+2] + h1.w*wl[4*kk+3];
                b1 += h1.x*wr[4*kk] + h1.y*wr[4*kk+1] + h1.z*wr[4*kk+2] + h1.w*wr[4*kk+3];
            }
            int rA = r0 + rr, rB = rA + 1;
            if (rA < n) { xl[(size_t)rA * D + lane] = a0; xr[(size_t)rA * D + lane] = b0; }
            if (rB < n) { xl[(size_t)rB * D + lane] = a1; xr[(size_t)rB * D + lane] = b1; }
        }
        // stage next group (data has arrived during compute)
        if (rn < n) {
            BN_ELU_APPLY(p0, p1)
            ((float4*)lp)[0] = p0; ((float4*)lp)[1] = p1;
        }
    }
}

// ---------------- fused GATv2 ----------------
// wave = contiguous, edge-balanced node range (wbeg); 16-lane group g = edge slot
// (4 edges/pack); lane owns 4 features. eas is pre-sorted edge_attr (CSR order).
// No online max (logits bounded; ratio identical to max-subtracted form).
// R5/R8 kernel verbatim — measured optimum of this structure:
//   80 VGPR / 6 waves/SIMD / ~117-122us. A/B evidence:
//   - R6: removing ea prefetch (68 VGPR, 7w) -> 147us. Prefetch is load-bearing ILP.
//   - R7: LDS-stat-atomics + b4-reload + readfirstlane trims (68 VGPR, 7w) -> 123us.
// Launch config STATIC (R7: occupancy API in kernel_launch broke graph capture).

#define EEVB(eb, j0) { \
    float4 u0 = *(const float4*)(lwp + (j0 + 0) * 64); \
    float4 u1 = *(const float4*)(lwp + (j0 + 1) * 64); \
    float4 u2 = *(const float4*)(lwp + (j0 + 2) * 64); \
    float4 u3 = *(const float4*)(lwp + (j0 + 3) * 64); \
    eex += eb.x*u0.x + eb.y*u1.x + eb.z*u2.x + eb.w*u3.x; \
    eey += eb.x*u0.y + eb.y*u1.y + eb.z*u2.y + eb.w*u3.y; \
    eez += eb.x*u0.z + eb.y*u1.z + eb.z*u2.z + eb.w*u3.z; \
    eew += eb.x*u0.w + eb.y*u1.w + eb.z*u2.w + eb.w*u3.w; }

__global__ __launch_bounds__(256) void k_gat(
        const float4* __restrict__ xl4, const float4* __restrict__ xr4,
        const float4* __restrict__ eas4, const int* __restrict__ srcs,
        const int* __restrict__ off, const int* __restrict__ wbeg,
        const float4* __restrict__ We4, const float4* __restrict__ att4,
        const float4* __restrict__ bias4, float* __restrict__ out,
        float* __restrict__ stat, int n, int do_elu) {
    __shared__ float ls[128];
    __shared__ float lwe[1024];             // We [16][64] staged once per block
    if (threadIdx.x < 128) ls[threadIdx.x] = 0.f;
    ((float4*)lwe)[threadIdx.x] = We4[threadIdx.x];   // 256 thr x 16B = 4 KB
    __syncthreads();
    int lane = threadIdx.x & 63;
    int g = lane >> 4, c16 = lane & 15;
    const float* lwp = lwe + c16 * 4;       // this lane's 4 output cols
    float4 av = att4[c16];
    float4 b4 = bias4[c16];
    int wid = blockIdx.x * (blockDim.x >> 6) + (threadIdx.x >> 6);
    int ns = wbeg[wid], nt = wbeg[wid + 1];
    float bsx = 0.f, bsy = 0.f, bsz = 0.f, bsw = 0.f;
    float bqx = 0.f, bqy = 0.f, bqz = 0.f, bqw = 0.f;
    int beg = (ns < nt) ? off[ns] : 0;
    for (int i = ns; i < nt; ++i) {
        int end = off[i + 1];
        int deg = end - beg;
        float4 xrv = xr4[i * 16 + c16];
        float denom = 0.f;
        float ax = 0.f, ay = 0.f, az = 0.f, aw = 0.f;
        float ex = 0.f, ey = 0.f, ez = 0.f, ew = 0.f;
        if (deg > 0) {
            // prologue: pack @ beg (srcs + ea + X all prefetched one iteration ahead)
            int actc = (g < deg);
            int p = beg + (actc ? g : 0);
            int s0 = srcs[p];
            int q = 4 * p;
            float4 e0 = eas4[q], e1 = eas4[q + 1], e2 = eas4[q + 2], e3 = eas4[q + 3];
            float4 X = xl4[s0 * 16 + c16];
            for (int pos = beg; pos < end; pos += 4) {
                int posn = pos + 4;
                int remn = end - posn;
                int actn = (remn > 0) && (g < remn);
                int pn = (remn > 0) ? posn + (actn ? g : 0) : pos;
                int sn = srcs[pn];                      // issue next srcs
                int qn = 4 * pn;                        // issue next ea (independent)
                float4 ne0 = eas4[qn],     ne1 = eas4[qn + 1];
                float4 ne2 = eas4[qn + 2], ne3 = eas4[qn + 3];
                // eev for current pack from LDS-we (covers sn latency)
                float eex = 0.f, eey = 0.f, eez = 0.f, eew = 0.f;
                EEVB(e0, 0) EEVB(e1, 4) EEVB(e2, 8) EEVB(e3, 12)
                // next xl gather (sn arrived during eev)
                float4 xn = xl4[sn * 16 + c16];
                float mk = actc ? 1.f : 0.f;
                ex += mk * eex; ey += mk * eey; ez += mk * eez; ew += mk * eew;
                float mx = X.x + xrv.x + eex;
                float my = X.y + xrv.y + eey;
                float mz = X.z + xrv.z + eez;
                float mw = X.w + xrv.w + eew;
                float p0 = fmaxf(mx, NEG * mx) * av.x
                         + fmaxf(my, NEG * my) * av.y
                         + fmaxf(mz, NEG * mz) * av.z
                         + fmaxf(mw, NEG * mw) * av.w;
                #pragma unroll
                for (int o = 1; o <= 8; o <<= 1) p0 += __shfl_xor(p0, o, 64);
                float ev = mk * __expf(p0);
                denom += ev;
                ax += ev * X.x;
                ay += ev * X.y;
                az += ev * X.z;
                aw += ev * X.w;
                e0 = ne0; e1 = ne1; e2 = ne2; e3 = ne3; X = xn; actc = actn;
            }
        }
        // merge 4 per-group partials (plain sums — no max bookkeeping)
        #pragma unroll
        for (int o = 16; o <= 32; o <<= 1) {
            denom += __shfl_xor(denom, o, 64);
            ax += __shfl_xor(ax, o, 64);
            ay += __shfl_xor(ay, o, 64);
            az += __shfl_xor(az, o, 64);
            aw += __shfl_xor(aw, o, 64);
            ex += __shfl_xor(ex, o, 64);
            ey += __shfl_xor(ey, o, 64);
            ez += __shfl_xor(ez, o, 64);
            ew += __shfl_xor(ew, o, 64);
        }
        // self-loop (loop_attr@We == mean of incoming eev; 0 if deg==0)
        float inv = (deg > 0) ? 1.f / (float)deg : 0.f;
        float4 xli = xl4[i * 16 + c16];
        float mx = xli.x + xrv.x + ex * inv;
        float my = xli.y + xrv.y + ey * inv;
        float mz = xli.z + xrv.z + ez * inv;
        float mw = xli.w + xrv.w + ew * inv;
        float p0 = fmaxf(mx, NEG * mx) * av.x
                 + fmaxf(my, NEG * my) * av.y
                 + fmaxf(mz, NEG * mz) * av.z
                 + fmaxf(mw, NEG * mw) * av.w;
        #pragma unroll
        for (int o = 1; o <= 8; o <<= 1) p0 += __shfl_xor(p0, o, 64);
        float ev = __expf(p0);
        denom += ev;
        ax += ev * xli.x;
        ay += ev * xli.y;
        az += ev * xli.z;
        aw += ev * xli.w;
        float invd = 1.f / denom;
        float ox = ax * invd + b4.x;
        float oy = ay * invd + b4.y;
        float oz = az * invd + b4.z;
        float ow = aw * invd + b4.w;
        if (do_elu) {
            ox = (ox > 0.f) ? ox : expm1f(ox);
            oy = (oy > 0.f) ? oy : expm1f(oy);
            oz = (oz > 0.f) ? oz : expm1f(oz);
            ow = (ow > 0.f) ? ow : expm1f(ow);
        }
        if (g == 0) {
            float4 o4; o4.x = ox; o4.y = oy; o4.z = oz; o4.w = ow;
            ((float4*)out)[i * 16 + c16] = o4;
            if (stat) {
                bsx += ox; bsy += oy; bsz += oz; bsw += ow;
                bqx += ox * ox; bqy += oy * oy; bqz += oz * oz; bqw += ow * ow;
            }
        }
        beg = end;
    }
    if (stat) {
        if (g == 0) {
            atomicAdd(&ls[c16 * 4 + 0], bsx);
            atomicAdd(&ls[c16 * 4 + 1], bsy);
            atomicAdd(&ls[c16 * 4 + 2], bsz);
            atomicAdd(&ls[c16 * 4 + 3], bsw);
            atomicAdd(&ls[64 + c16 * 4 + 0], bqx);
            atomicAdd(&ls[64 + c16 * 4 + 1], bqy);
            atomicAdd(&ls[64 + c16 * 4 + 2], bqz);
            atomicAdd(&ls[64 + c16 * 4 + 3], bqw);
        }
        __syncthreads();
        if (threadIdx.x < 128) atomicAdd(&stat[threadIdx.x], ls[threadIdx.x]);
    }
}

// ---------------- launch ----------------

extern "C" void kernel_launch(void* const* d_in, const int* in_sizes, int n_in,
                              void* d_out, int out_size, void* d_ws, size_t ws_size,
                              hipStream_t stream) {
    const float* x     = (const float*)d_in[0];
    const int*   ei    = (const int*)d_in[1];
    const float* ea    = (const float*)d_in[2];
    const float* Wl    = (const float*)d_in[3];
    const float* Wr    = (const float*)d_in[4];
    const float* We    = (const float*)d_in[5];
    const float* att   = (const float*)d_in[6];
    const float* bias  = (const float*)d_in[7];
    const float* gamma = (const float*)d_in[8];
    const float* beta  = (const float*)d_in[9];
    float* out = (float*)d_out;

    int n = in_sizes[0] / D;
    int e = in_sizes[1] / 2;
    const int* src = ei;
    const int* dst = ei + e;
    int nb = (n + 1023) / 1024;

    float* xl   = (float*)d_ws;
    float* xr   = xl + (size_t)n * D;
    float* hbuf = xr + (size_t)n * D;
    float* stat = hbuf + (size_t)n * D;        // [2][128]: raw {sum,sq} per BN
    float* eas  = stat + 256;                   // [e][16] pre-sorted edge_attr
    int* cnt  = (int*)(eas + (size_t)e * ED);
    int* fill = cnt + n;                        // adjacent to cnt: one memset
    int* off  = fill + n;
    int* bsum = off + n + 1;
    int* srcs = bsum + 256;
    int* wbeg = srcs + e;                       // [nw+1] edge-balanced partition

    // STATIC grids (R7 lesson: no runtime queries in kernel_launch).
    // k_gat VGPR=80 (R5/R8 measured) -> 6 waves/SIMD -> 6 blocks/CU: 1536.
    const int gat_grid  = 1536;
    const int nw = gat_grid * 4;                // waves in k_gat
    const int gemm_grid = 512;                  // 3-4 grid-stride iters/wave (R6 win)

    hipMemsetAsync(cnt, 0, (size_t)(2 * n) * sizeof(int), stream);
    k_count<<<(e + 255) / 256, 256, 0, stream>>>(dst, cnt, stat, e);
    k_scan1<<<nb, 1024, 0, stream>>>(cnt, off, bsum, n);
    k_scan2<<<1, 64, 0, stream>>>(bsum, nb);
    k_scan3<<<(n + 255) / 256, 256, 0, stream>>>(off, bsum, n);
    k_part<<<(nw + 1 + 255) / 256, 256, 0, stream>>>(off, wbeg, n, nw);
    k_scatter<<<(e + 255) / 256, 256, 0, stream>>>(src, dst, off, fill, srcs,
                                                   (float4*)eas, (const float4*)ea, e);

    // layer 0: conv -> ELU (in gat) -> BN0 stats (epilogue); BN0 apply folded into gemm1
    k_gemm<<<gemm_grid, 256, 0, stream>>>(x, Wl, Wr, xl, xr, stat, gamma, beta, 0, n);
    k_gat<<<gat_grid, 256, 0, stream>>>((const float4*)xl, (const float4*)xr,
                                        (const float4*)eas, srcs, off, wbeg,
                                        (const float4*)We, (const float4*)att,
                                        (const float4*)bias, hbuf, stat, n, 1);
    // layer 1: conv (BN0 folded) -> BN1 stats (epilogue); BN1+ELU folded into gemm2
    k_gemm<<<gemm_grid, 256, 0, stream>>>(hbuf, Wl + D * D, Wr + D * D, xl, xr,
                                          stat, gamma, beta, 1, n);
    k_gat<<<gat_grid, 256, 0, stream>>>((const float4*)xl, (const float4*)xr,
                                        (const float4*)eas, srcs, off, wbeg,
                                        (const float4*)(We + ED * D), (const float4*)(att + D),
                                        (const float4*)(bias + D), hbuf, stat + 128, n, 0);
    // layer 2: conv (BN1+ELU folded) -> out
    k_gemm<<<gemm_grid, 256, 0, stream>>>(hbuf, Wl + 2 * D * D, Wr + 2 * D * D, xl, xr,
                                          stat + 128, gamma + D, beta + D, 2, n);
    k_gat<<<gat_grid, 256, 0, stream>>>((const float4*)xl, (const float4*)xr,
                                        (const float4*)eas, srcs, off, wbeg,
                                        (const float4*)(We + 2 * ED * D), (const float4*)(att + 2 * D),
                                        (const float4*)(bias + 2 * D), out, (float*)nullptr, n, 0);
}

// Round 11
// 565.619 us; speedup vs baseline: 1.7236x; 1.0606x over previous
//
#include <hip/hip_runtime.h>
#include <math.h>

#define D 64
#define ED 16
#define NEG 0.2f
#define BN_EPS 1e-5f

// ---------------- CSR construction ----------------

__global__ void k_count(const int* __restrict__ dst, int* __restrict__ cnt,
                        float* __restrict__ stat, int e) {
    int i = blockIdx.x * blockDim.x + threadIdx.x;
    if (blockIdx.x == 0 && threadIdx.x < 256) stat[threadIdx.x] = 0.f;  // zero BN stat bufs
    if (i < e) atomicAdd(&cnt[dst[i]], 1);
}

__global__ void k_scan1(const int* __restrict__ cnt, int* __restrict__ off,
                        int* __restrict__ bsum, int n) {
    __shared__ int buf[1024];
    int i = blockIdx.x * 1024 + threadIdx.x;
    int v = (i < n) ? cnt[i] : 0;
    buf[threadIdx.x] = v;
    __syncthreads();
    for (int d = 1; d < 1024; d <<= 1) {
        int t = (threadIdx.x >= (unsigned)d) ? buf[threadIdx.x - d] : 0;
        __syncthreads();
        buf[threadIdx.x] += t;
        __syncthreads();
    }
    if (i < n) off[i + 1] = buf[threadIdx.x];
    if (threadIdx.x == 1023) bsum[blockIdx.x] = buf[1023];
    if (i == 0) off[0] = 0;
}

// scan2 folded in: every block redundantly wave-scans the <=49 block sums (cheap),
// removing one kernel launch from the per-iteration graph.
__global__ void k_scan3(int* __restrict__ off, const int* __restrict__ bsum,
                        int n, int nb) {
    __shared__ int pfx[64];
    int t = threadIdx.x;
    if (t < 64) {
        int v = (t < nb) ? bsum[t] : 0;
        #pragma unroll
        for (int o = 1; o < 64; o <<= 1) {
            int u = __shfl_up(v, o, 64);
            if (t >= o) v += u;
        }
        int ex = __shfl_up(v, 1, 64);
        pfx[t] = (t == 0) ? 0 : ex;
    }
    __syncthreads();
    int i = blockIdx.x * blockDim.x + t;
    if (i < n) off[i + 1] += pfx[i >> 10];
}

// scatter src index AND edge_attr row into CSR (dst-sorted) order.
// k_part folded in (first nwv+1 threads): edge-balanced wave partition,
// wbeg[w] = first node of wave w's contiguous range; weight(node) = deg + C.
__global__ void k_scatter(const int* __restrict__ src, const int* __restrict__ dst,
                          const int* __restrict__ off, int* __restrict__ fill,
                          int* __restrict__ srcs, float4* __restrict__ eas4,
                          const float4* __restrict__ ea4, int e,
                          int* __restrict__ wbeg, int nwv, int n) {
    int i = blockIdx.x * blockDim.x + threadIdx.x;
    if (i <= nwv) {
        const long long C = 6;
        long long total = (long long)off[n] + C * n;
        long long target = (total * i) / nwv;
        int lo = 0, hi = n;
        while (lo < hi) {
            int mid = (lo + hi) >> 1;
            long long f = (long long)off[mid] + C * mid;
            if (f < target) lo = mid + 1; else hi = mid;
        }
        wbeg[i] = lo;
    }
    if (i < e) {
        int d = dst[i];
        size_t qi = 4 * (size_t)i;
        float4 a0 = ea4[qi], a1 = ea4[qi + 1], a2 = ea4[qi + 2], a3 = ea4[qi + 3];
        int p = off[d] + atomicAdd(&fill[d], 1);
        srcs[p] = src[i];
        int qp = 4 * p;
        eas4[qp] = a0; eas4[qp + 1] = a1; eas4[qp + 2] = a2; eas4[qp + 3] = a3;
    }
}

// ---------------- gemm: xl/xr = BN'(h) @ {Wl,Wr}; BN finalize folded in ----------------
// mode: 0 = plain, 1 = BN, 2 = BN+ELU. stat points at this layer's raw {sum[64],sq[64]}.
// Broadcast via per-wave LDS staging + wave-uniform ds_read_b128 (R4: kept).
// R9 software double-buffer kept (neutral vs R8, harmless). gemm_grid=512 (R6 win).
// DEFAULT launch bounds (R2 lesson: never cap a reg-heavy kernel).

#define BN_ELU_APPLY(v0, v1) { \
    if (mode) { \
        v0.x = v0.x * scs[0] + shs[0]; v0.y = v0.y * scs[1] + shs[1]; \
        v0.z = v0.z * scs[2] + shs[2]; v0.w = v0.w * scs[3] + shs[3]; \
        v1.x = v1.x * scs[4] + shs[4]; v1.y = v1.y * scs[5] + shs[5]; \
        v1.z = v1.z * scs[6] + shs[6]; v1.w = v1.w * scs[7] + shs[7]; \
        if (mode == 2) { \
            v0.x = (v0.x > 0.f) ? v0.x : expm1f(v0.x); \
            v0.y = (v0.y > 0.f) ? v0.y : expm1f(v0.y); \
            v0.z = (v0.z > 0.f) ? v0.z : expm1f(v0.z); \
            v0.w = (v0.w > 0.f) ? v0.w : expm1f(v0.w); \
            v1.x = (v1.x > 0.f) ? v1.x : expm1f(v1.x); \
            v1.y = (v1.y > 0.f) ? v1.y : expm1f(v1.y); \
            v1.z = (v1.z > 0.f) ? v1.z : expm1f(v1.z); \
            v1.w = (v1.w > 0.f) ? v1.w : expm1f(v1.w); \
        } \
    } }

__global__ __launch_bounds__(256) void k_gemm(
        const float* __restrict__ h, const float* __restrict__ Wl,
        const float* __restrict__ Wr, float* __restrict__ xl,
        float* __restrict__ xr, const float* __restrict__ stat,
        const float* __restrict__ gamma, const float* __restrict__ beta,
        int mode, int n) {
    __shared__ float lh[4][512];            // 8 rows x 64 cols per wave
    int lane = threadIdx.x & 63;
    int w = threadIdx.x >> 6;
    float wl[D], wr[D];
    #pragma unroll
    for (int k = 0; k < D; ++k) { wl[k] = Wl[k * D + lane]; wr[k] = Wr[k * D + lane]; }
    // staging role: lane l stages row (l>>3), cols (l&7)*8 .. +7 (2 float4)
    int srow = lane >> 3, scol = (lane & 7) * 8;
    float scs[8], shs[8];
    #pragma unroll
    for (int j = 0; j < 8; ++j) { scs[j] = 1.f; shs[j] = 0.f; }
    if (mode) {
        #pragma unroll
        for (int j = 0; j < 8; ++j) {
            int c = scol + j;
            float s = stat[c], q = stat[64 + c];
            float mean = s / (float)n;
            float var  = q / (float)n - mean * mean;
            float scv = gamma[c] * rsqrtf(var + BN_EPS);
            scs[j] = scv; shs[j] = beta[c] - mean * scv;
        }
    }
    int wid = blockIdx.x * 4 + w;
    int stride = gridDim.x * 4 * 8;
    int r0 = wid * 8;
    float* lp = &lh[w][srow * 64 + scol];
    if (r0 < n) {
        // prologue: stage group r0
        int r = r0 + srow;
        float4 v0 = make_float4(0.f, 0.f, 0.f, 0.f);
        float4 v1 = make_float4(0.f, 0.f, 0.f, 0.f);
        if (r < n) {
            const float4* hp = (const float4*)(h + (size_t)r * D + scol);
            v0 = hp[0]; v1 = hp[1];
        }
        BN_ELU_APPLY(v0, v1)
        ((float4*)lp)[0] = v0; ((float4*)lp)[1] = v1;
    }
    for (; r0 < n; r0 += stride) {
        int rn = r0 + stride;
        // issue next group's loads FIRST (latency hides under this group's compute)
        float4 p0 = make_float4(0.f, 0.f, 0.f, 0.f);
        float4 p1 = make_float4(0.f, 0.f, 0.f, 0.f);
        if (rn < n) {
            int r = rn + srow;
            if (r < n) {
                const float4* hp = (const float4*)(h + (size_t)r * D + scol);
                p0 = hp[0]; p1 = hp[1];
            }
        }
        // compute current group from LDS (same-wave write->read is in-order)
        #pragma unroll
        for (int rr = 0; rr < 8; rr += 2) {
            const float4* row0 = (const float4*)&lh[w][rr * 64];
            const float4* row1 = (const float4*)&lh[w][rr * 64 + 64];
            float a0 = 0.f, b0 = 0.f, a1 = 0.f, b1 = 0.f;
            #pragma unroll
            for (int kk = 0; kk < 16; ++kk) {
                float4 h0 = row0[kk];       // uniform address -> broadcast
                float4 h1 = row1[kk];
                a0 += h0.x*wl[4*kk] + h0.y*wl[4*kk+1] + h0.z*wl[4*kk+2] + h0.w*wl[4*kk+3];
                b0 += h0.x*wr[4*kk] + h0.y*wr[4*kk+1] + h0.z*wr[4*kk+2] + h0.w*wr[4*kk+3];
                a1 += h1.x*wl[4*kk] + h1.y*wl[4*kk+1] + h1.z*wl[4*kk+2] + h1.w*wl[4*kk+3];
                b1 += h1.x*wr[4*kk] + h1.y*wr[4*kk+1] + h1.z*wr[4*kk+2] + h1.w*wr[4*kk+3];
            }
            int rA = r0 + rr, rB = rA + 1;
            if (rA < n) { xl[(size_t)rA * D + lane] = a0; xr[(size_t)rA * D + lane] = b0; }
            if (rB < n) { xl[(size_t)rB * D + lane] = a1; xr[(size_t)rB * D + lane] = b1; }
        }
        // stage next group (data has arrived during compute)
        if (rn < n) {
            BN_ELU_APPLY(p0, p1)
            ((float4*)lp)[0] = p0; ((float4*)lp)[1] = p1;
        }
    }
}

// ---------------- fused GATv2 ----------------
// wave = contiguous, edge-balanced node range (wbeg); 16-lane group g = edge slot
// (4 edges/pack); lane owns 4 features. eas is pre-sorted edge_attr (CSR order).
// No online max (logits bounded; ratio identical to max-subtracted form).
// R5/R8 structure (80 VGPR / 6 waves/SIMD — measured optimum; R6/R7 A/Bs).
// R10/R11: the 16-lane logit reduce moves from __shfl_xor (ds_bpermute -> DS
// pipe, lgkm-waited, serial) to DPP row ops (VALU pipe, no lgkm wait). R10's
// build likely failed because the DPP ctrl was a runtime function arg —
// __builtin_amdgcn_update_dpp requires integer-constant args; now a template
// parameter (guaranteed ICE). Sequence: quad_perm[1,0,3,2]=0xB1 (xor1),
// quad_perm[2,3,0,1]=0x4E (xor2), row_ror:4=0x124, row_ror:8=0x128 — after the
// 4 add-steps every lane of each 16-lane row holds the row sum.

template <int CTRL>
__device__ __forceinline__ float dpp_row_add(float x) {
    int yi = __builtin_amdgcn_update_dpp(0, __float_as_int(x), CTRL, 0xF, 0xF, true);
    return x + __int_as_float(yi);
}
__device__ __forceinline__ float row16_reduce(float x) {
    x = dpp_row_add<0xB1>(x);    // quad_perm [1,0,3,2]  (xor 1)
    x = dpp_row_add<0x4E>(x);    // quad_perm [2,3,0,1]  (xor 2)
    x = dpp_row_add<0x124>(x);   // row_ror:4  (adjacent quad partial)
    x = dpp_row_add<0x128>(x);   // row_ror:8  (full row sum, all lanes)
    return x;
}

#define EEVB(eb, j0) { \
    float4 u0 = *(const float4*)(lwp + (j0 + 0) * 64); \
    float4 u1 = *(const float4*)(lwp + (j0 + 1) * 64); \
    float4 u2 = *(const float4*)(lwp + (j0 + 2) * 64); \
    float4 u3 = *(const float4*)(lwp + (j0 + 3) * 64); \
    eex += eb.x*u0.x + eb.y*u1.x + eb.z*u2.x + eb.w*u3.x; \
    eey += eb.x*u0.y + eb.y*u1.y + eb.z*u2.y + eb.w*u3.y; \
    eez += eb.x*u0.z + eb.y*u1.z + eb.z*u2.z + eb.w*u3.z; \
    eew += eb.x*u0.w + eb.y*u1.w + eb.z*u2.w + eb.w*u3.w; }

__global__ __launch_bounds__(256) void k_gat(
        const float4* __restrict__ xl4, const float4* __restrict__ xr4,
        const float4* __restrict__ eas4, const int* __restrict__ srcs,
        const int* __restrict__ off, const int* __restrict__ wbeg,
        const float4* __restrict__ We4, const float4* __restrict__ att4,
        const float4* __restrict__ bias4, float* __restrict__ out,
        float* __restrict__ stat, int n, int do_elu) {
    __shared__ float ls[128];
    __shared__ float lwe[1024];             // We [16][64] staged once per block
    if (threadIdx.x < 128) ls[threadIdx.x] = 0.f;
    ((float4*)lwe)[threadIdx.x] = We4[threadIdx.x];   // 256 thr x 16B = 4 KB
    __syncthreads();
    int lane = threadIdx.x & 63;
    int g = lane >> 4, c16 = lane & 15;
    const float* lwp = lwe + c16 * 4;       // this lane's 4 output cols
    float4 av = att4[c16];
    float4 b4 = bias4[c16];
    int wid = blockIdx.x * (blockDim.x >> 6) + (threadIdx.x >> 6);
    int ns = wbeg[wid], nt = wbeg[wid + 1];
    float bsx = 0.f, bsy = 0.f, bsz = 0.f, bsw = 0.f;
    float bqx = 0.f, bqy = 0.f, bqz = 0.f, bqw = 0.f;
    int beg = (ns < nt) ? off[ns] : 0;
    for (int i = ns; i < nt; ++i) {
        int end = off[i + 1];
        int deg = end - beg;
        float4 xrv = xr4[i * 16 + c16];
        float denom = 0.f;
        float ax = 0.f, ay = 0.f, az = 0.f, aw = 0.f;
        float ex = 0.f, ey = 0.f, ez = 0.f, ew = 0.f;
        if (deg > 0) {
            // prologue: pack @ beg (srcs + ea + X all prefetched one iteration ahead)
            int actc = (g < deg);
            int p = beg + (actc ? g : 0);
            int s0 = srcs[p];
            int q = 4 * p;
            float4 e0 = eas4[q], e1 = eas4[q + 1], e2 = eas4[q + 2], e3 = eas4[q + 3];
            float4 X = xl4[s0 * 16 + c16];
            for (int pos = beg; pos < end; pos += 4) {
                int posn = pos + 4;
                int remn = end - posn;
                int actn = (remn > 0) && (g < remn);
                int pn = (remn > 0) ? posn + (actn ? g : 0) : pos;
                int sn = srcs[pn];                      // issue next srcs
                int qn = 4 * pn;                        // issue next ea (independent)
                float4 ne0 = eas4[qn],     ne1 = eas4[qn + 1];
                float4 ne2 = eas4[qn + 2], ne3 = eas4[qn + 3];
                // eev for current pack from LDS-we (covers sn latency)
                float eex = 0.f, eey = 0.f, eez = 0.f, eew = 0.f;
                EEVB(e0, 0) EEVB(e1, 4) EEVB(e2, 8) EEVB(e3, 12)
                // next xl gather (sn arrived during eev)
                float4 xn = xl4[sn * 16 + c16];
                float mk = actc ? 1.f : 0.f;
                ex += mk * eex; ey += mk * eey; ez += mk * eez; ew += mk * eew;
                float mx = X.x + xrv.x + eex;
                float my = X.y + xrv.y + eey;
                float mz = X.z + xrv.z + eez;
                float mw = X.w + xrv.w + eew;
                float p0 = fmaxf(mx, NEG * mx) * av.x
                         + fmaxf(my, NEG * my) * av.y
                         + fmaxf(mz, NEG * mz) * av.z
                         + fmaxf(mw, NEG * mw) * av.w;
                p0 = row16_reduce(p0);                  // DPP: VALU-pipe row sum
                float ev = mk * __expf(p0);
                denom += ev;
                ax += ev * X.x;
                ay += ev * X.y;
                az += ev * X.z;
                aw += ev * X.w;
                e0 = ne0; e1 = ne1; e2 = ne2; e3 = ne3; X = xn; actc = actn;
            }
        }
        // merge 4 per-group partials (plain sums — no max bookkeeping)
        #pragma unroll
        for (int o = 16; o <= 32; o <<= 1) {
            denom += __shfl_xor(denom, o, 64);
            ax += __shfl_xor(ax, o, 64);
            ay += __shfl_xor(ay, o, 64);
            az += __shfl_xor(az, o, 64);
            aw += __shfl_xor(aw, o, 64);
            ex += __shfl_xor(ex, o, 64);
            ey += __shfl_xor(ey, o, 64);
            ez += __shfl_xor(ez, o, 64);
            ew += __shfl_xor(ew, o, 64);
        }
        // self-loop (loop_attr@We == mean of incoming eev; 0 if deg==0)
        float inv = (deg > 0) ? 1.f / (float)deg : 0.f;
        float4 xli = xl4[i * 16 + c16];
        float mx = xli.x + xrv.x + ex * inv;
        float my = xli.y + xrv.y + ey * inv;
        float mz = xli.z + xrv.z + ez * inv;
        float mw = xli.w + xrv.w + ew * inv;
        float p0 = fmaxf(mx, NEG * mx) * av.x
                 + fmaxf(my, NEG * my) * av.y
                 + fmaxf(mz, NEG * mz) * av.z
                 + fmaxf(mw, NEG * mw) * av.w;
        p0 = row16_reduce(p0);                          // DPP row sum
        float ev = __expf(p0);
        denom += ev;
        ax += ev * xli.x;
        ay += ev * xli.y;
        az += ev * xli.z;
        aw += ev * xli.w;
        float invd = 1.f / denom;
        float ox = ax * invd + b4.x;
        float oy = ay * invd + b4.y;
        float oz = az * invd + b4.z;
        float ow = aw * invd + b4.w;
        if (do_elu) {
            ox = (ox > 0.f) ? ox : expm1f(ox);
            oy = (oy > 0.f) ? oy : expm1f(oy);
            oz = (oz > 0.f) ? oz : expm1f(oz);
            ow = (ow > 0.f) ? ow : expm1f(ow);
        }
        if (g == 0) {
            float4 o4; o4.x = ox; o4.y = oy; o4.z = oz; o4.w = ow;
            ((float4*)out)[i * 16 + c16] = o4;
            if (stat) {
                bsx += ox; bsy += oy; bsz += oz; bsw += ow;
                bqx += ox * ox; bqy += oy * oy; bqz += oz * oz; bqw += ow * ow;
            }
        }
        beg = end;
    }
    if (stat) {
        if (g == 0) {
            atomicAdd(&ls[c16 * 4 + 0], bsx);
            atomicAdd(&ls[c16 * 4 + 1], bsy);
            atomicAdd(&ls[c16 * 4 + 2], bsz);
            atomicAdd(&ls[c16 * 4 + 3], bsw);
            atomicAdd(&ls[64 + c16 * 4 + 0], bqx);
            atomicAdd(&ls[64 + c16 * 4 + 1], bqy);
            atomicAdd(&ls[64 + c16 * 4 + 2], bqz);
            atomicAdd(&ls[64 + c16 * 4 + 3], bqw);
        }
        __syncthreads();
        if (threadIdx.x < 128) atomicAdd(&stat[threadIdx.x], ls[threadIdx.x]);
    }
}

// ---------------- launch ----------------

extern "C" void kernel_launch(void* const* d_in, const int* in_sizes, int n_in,
                              void* d_out, int out_size, void* d_ws, size_t ws_size,
                              hipStream_t stream) {
    const float* x     = (const float*)d_in[0];
    const int*   ei    = (const int*)d_in[1];
    const float* ea    = (const float*)d_in[2];
    const float* Wl    = (const float*)d_in[3];
    const float* Wr    = (const float*)d_in[4];
    const float* We    = (const float*)d_in[5];
    const float* att   = (const float*)d_in[6];
    const float* bias  = (const float*)d_in[7];
    const float* gamma = (const float*)d_in[8];
    const float* beta  = (const float*)d_in[9];
    float* out = (float*)d_out;

    int n = in_sizes[0] / D;
    int e = in_sizes[1] / 2;
    const int* src = ei;
    const int* dst = ei + e;
    int nb = (n + 1023) / 1024;

    float* xl   = (float*)d_ws;
    float* xr   = xl + (size_t)n * D;
    float* hbuf = xr + (size_t)n * D;
    float* stat = hbuf + (size_t)n * D;        // [2][128]: raw {sum,sq} per BN
    float* eas  = stat + 256;                   // [e][16] pre-sorted edge_attr
    int* cnt  = (int*)(eas + (size_t)e * ED);
    int* fill = cnt + n;                        // adjacent to cnt: one memset
    int* off  = fill + n;
    int* bsum = off + n + 1;
    int* srcs = bsum + 256;
    int* wbeg = srcs + e;                       // [nw+1] edge-balanced partition

    // STATIC grids (R7 lesson: no runtime queries in kernel_launch).
    // k_gat VGPR=80 (R5/R8 measured) -> 6 waves/SIMD -> 6 blocks/CU: 1536.
    const int gat_grid  = 1536;
    const int nw = gat_grid * 4;                // waves in k_gat
    const int gemm_grid = 512;                  // 3-4 grid-stride iters/wave (R6 win)

    hipMemsetAsync(cnt, 0, (size_t)(2 * n) * sizeof(int), stream);
    k_count<<<(e + 255) / 256, 256, 0, stream>>>(dst, cnt, stat, e);
    k_scan1<<<nb, 1024, 0, stream>>>(cnt, off, bsum, n);
    k_scan3<<<(n + 255) / 256, 256, 0, stream>>>(off, bsum, n, nb);
    k_scatter<<<(e + 255) / 256, 256, 0, stream>>>(src, dst, off, fill, srcs,
                                                   (float4*)eas, (const float4*)ea, e,
                                                   wbeg, nw, n);

    // layer 0: conv -> ELU (in gat) -> BN0 stats (epilogue); BN0 apply folded into gemm1
    k_gemm<<<gemm_grid, 256, 0, stream>>>(x, Wl, Wr, xl, xr, stat, gamma, beta, 0, n);
    k_gat<<<gat_grid, 256, 0, stream>>>((const float4*)xl, (const float4*)xr,
                                        (const float4*)eas, srcs, off, wbeg,
                                        (const float4*)We, (const float4*)att,
                                        (const float4*)bias, hbuf, stat, n, 1);
    // layer 1: conv (BN0 folded) -> BN1 stats (epilogue); BN1+ELU folded into gemm2
    k_gemm<<<gemm_grid, 256, 0, stream>>>(hbuf, Wl + D * D, Wr + D * D, xl, xr,
                                          stat, gamma, beta, 1, n);
    k_gat<<<gat_grid, 256, 0, stream>>>((const float4*)xl, (const float4*)xr,
                                        (const float4*)eas, srcs, off, wbeg,
                                        (const float4*)(We + ED * D), (const float4*)(att + D),
                                        (const float4*)(bias + D), hbuf, stat + 128, n, 0);
    // layer 2: conv (BN1+ELU folded) -> out
    k_gemm<<<gemm_grid, 256, 0, stream>>>(hbuf, Wl + 2 * D * D, Wr + 2 * D * D, xl, xr,
                                          stat + 128, gamma + D, beta + D, 2, n);
    k_gat<<<gat_grid, 256, 0, stream>>>((const float4*)xl, (const float4*)xr,
                                        (const float4*)eas, srcs, off, wbeg,
                                        (const float4*)(We + 2 * ED * D), (const float4*)(att + 2 * D),
                                        (const float4*)(bias + 2 * D), out, (float*)nullptr, n, 0);
}

// Round 12
// 534.464 us; speedup vs baseline: 1.8240x; 1.0583x over previous
//
#include <hip/hip_runtime.h>
#include <math.h>

#define D 64
#define ED 16
#define NEG 0.2f
#define BN_EPS 1e-5f

// ---------------- CSR construction ----------------

__global__ void k_count(const int* __restrict__ dst, int* __restrict__ cnt,
                        float* __restrict__ stat, int e) {
    int i = blockIdx.x * blockDim.x + threadIdx.x;
    if (blockIdx.x == 0 && threadIdx.x < 256) stat[threadIdx.x] = 0.f;  // zero BN stat bufs
    if (i < e) atomicAdd(&cnt[dst[i]], 1);
}

__global__ void k_scan1(const int* __restrict__ cnt, int* __restrict__ off,
                        int* __restrict__ bsum, int n) {
    __shared__ int buf[1024];
    int i = blockIdx.x * 1024 + threadIdx.x;
    int v = (i < n) ? cnt[i] : 0;
    buf[threadIdx.x] = v;
    __syncthreads();
    for (int d = 1; d < 1024; d <<= 1) {
        int t = (threadIdx.x >= (unsigned)d) ? buf[threadIdx.x - d] : 0;
        __syncthreads();
        buf[threadIdx.x] += t;
        __syncthreads();
    }
    if (i < n) off[i + 1] = buf[threadIdx.x];
    if (threadIdx.x == 1023) bsum[blockIdx.x] = buf[1023];
    if (i == 0) off[0] = 0;
}

// scan2 folded in: every block redundantly wave-scans the <=49 block sums (cheap),
// removing one kernel launch from the per-iteration graph.
__global__ void k_scan3(int* __restrict__ off, const int* __restrict__ bsum,
                        int n, int nb) {
    __shared__ int pfx[64];
    int t = threadIdx.x;
    if (t < 64) {
        int v = (t < nb) ? bsum[t] : 0;
        #pragma unroll
        for (int o = 1; o < 64; o <<= 1) {
            int u = __shfl_up(v, o, 64);
            if (t >= o) v += u;
        }
        int ex = __shfl_up(v, 1, 64);
        pfx[t] = (t == 0) ? 0 : ex;
    }
    __syncthreads();
    int i = blockIdx.x * blockDim.x + t;
    if (i < n) off[i + 1] += pfx[i >> 10];
}

// scatter src index AND edge_attr row into CSR (dst-sorted) order.
// k_part folded in (first nwv+1 threads): edge-balanced wave partition,
// wbeg[w] = first node of wave w's contiguous range; weight(node) = deg + C.
__global__ void k_scatter(const int* __restrict__ src, const int* __restrict__ dst,
                          const int* __restrict__ off, int* __restrict__ fill,
                          int* __restrict__ srcs, float4* __restrict__ eas4,
                          const float4* __restrict__ ea4, int e,
                          int* __restrict__ wbeg, int nwv, int n) {
    int i = blockIdx.x * blockDim.x + threadIdx.x;
    if (i <= nwv) {
        const long long C = 6;
        long long total = (long long)off[n] + C * n;
        long long target = (total * i) / nwv;
        int lo = 0, hi = n;
        while (lo < hi) {
            int mid = (lo + hi) >> 1;
            long long f = (long long)off[mid] + C * mid;
            if (f < target) lo = mid + 1; else hi = mid;
        }
        wbeg[i] = lo;
    }
    if (i < e) {
        int d = dst[i];
        size_t qi = 4 * (size_t)i;
        float4 a0 = ea4[qi], a1 = ea4[qi + 1], a2 = ea4[qi + 2], a3 = ea4[qi + 3];
        int p = off[d] + atomicAdd(&fill[d], 1);
        srcs[p] = src[i];
        int qp = 4 * p;
        eas4[qp] = a0; eas4[qp + 1] = a1; eas4[qp + 2] = a2; eas4[qp + 3] = a3;
    }
}

// ---------------- gemm: xl/xr = BN'(h) @ {Wl,Wr}; BN finalize folded in ----------------
// mode: 0 = plain, 1 = BN, 2 = BN+ELU. stat points at this layer's raw {sum[64],sq[64]}.
// Broadcast via per-wave LDS staging + wave-uniform ds_read_b128 (R4: kept).
// R9 software double-buffer kept (neutral vs R8, harmless). gemm_grid=512 (R6 win).
// DEFAULT launch bounds (R2 lesson: never cap a reg-heavy kernel below its need).

#define BN_ELU_APPLY(v0, v1) { \
    if (mode) { \
        v0.x = v0.x * scs[0] + shs[0]; v0.y = v0.y * scs[1] + shs[1]; \
        v0.z = v0.z * scs[2] + shs[2]; v0.w = v0.w * scs[3] + shs[3]; \
        v1.x = v1.x * scs[4] + shs[4]; v1.y = v1.y * scs[5] + shs[5]; \
        v1.z = v1.z * scs[6] + shs[6]; v1.w = v1.w * scs[7] + shs[7]; \
        if (mode == 2) { \
            v0.x = (v0.x > 0.f) ? v0.x : expm1f(v0.x); \
            v0.y = (v0.y > 0.f) ? v0.y : expm1f(v0.y); \
            v0.z = (v0.z > 0.f) ? v0.z : expm1f(v0.z); \
            v0.w = (v0.w > 0.f) ? v0.w : expm1f(v0.w); \
            v1.x = (v1.x > 0.f) ? v1.x : expm1f(v1.x); \
            v1.y = (v1.y > 0.f) ? v1.y : expm1f(v1.y); \
            v1.z = (v1.z > 0.f) ? v1.z : expm1f(v1.z); \
            v1.w = (v1.w > 0.f) ? v1.w : expm1f(v1.w); \
        } \
    } }

__global__ __launch_bounds__(256) void k_gemm(
        const float* __restrict__ h, const float* __restrict__ Wl,
        const float* __restrict__ Wr, float* __restrict__ xl,
        float* __restrict__ xr, const float* __restrict__ stat,
        const float* __restrict__ gamma, const float* __restrict__ beta,
        int mode, int n) {
    __shared__ float lh[4][512];            // 8 rows x 64 cols per wave
    int lane = threadIdx.x & 63;
    int w = threadIdx.x >> 6;
    float wl[D], wr[D];
    #pragma unroll
    for (int k = 0; k < D; ++k) { wl[k] = Wl[k * D + lane]; wr[k] = Wr[k * D + lane]; }
    // staging role: lane l stages row (l>>3), cols (l&7)*8 .. +7 (2 float4)
    int srow = lane >> 3, scol = (lane & 7) * 8;
    float scs[8], shs[8];
    #pragma unroll
    for (int j = 0; j < 8; ++j) { scs[j] = 1.f; shs[j] = 0.f; }
    if (mode) {
        #pragma unroll
        for (int j = 0; j < 8; ++j) {
            int c = scol + j;
            float s = stat[c], q = stat[64 + c];
            float mean = s / (float)n;
            float var  = q / (float)n - mean * mean;
            float scv = gamma[c] * rsqrtf(var + BN_EPS);
            scs[j] = scv; shs[j] = beta[c] - mean * scv;
        }
    }
    int wid = blockIdx.x * 4 + w;
    int stride = gridDim.x * 4 * 8;
    int r0 = wid * 8;
    float* lp = &lh[w][srow * 64 + scol];
    if (r0 < n) {
        // prologue: stage group r0
        int r = r0 + srow;
        float4 v0 = make_float4(0.f, 0.f, 0.f, 0.f);
        float4 v1 = make_float4(0.f, 0.f, 0.f, 0.f);
        if (r < n) {
            const float4* hp = (const float4*)(h + (size_t)r * D + scol);
            v0 = hp[0]; v1 = hp[1];
        }
        BN_ELU_APPLY(v0, v1)
        ((float4*)lp)[0] = v0; ((float4*)lp)[1] = v1;
    }
    for (; r0 < n; r0 += stride) {
        int rn = r0 + stride;
        // issue next group's loads FIRST (latency hides under this group's compute)
        float4 p0 = make_float4(0.f, 0.f, 0.f, 0.f);
        float4 p1 = make_float4(0.f, 0.f, 0.f, 0.f);
        if (rn < n) {
            int r = rn + srow;
            if (r < n) {
                const float4* hp = (const float4*)(h + (size_t)r * D + scol);
                p0 = hp[0]; p1 = hp[1];
            }
        }
        // compute current group from LDS (same-wave write->read is in-order)
        #pragma unroll
        for (int rr = 0; rr < 8; rr += 2) {
            const float4* row0 = (const float4*)&lh[w][rr * 64];
            const float4* row1 = (const float4*)&lh[w][rr * 64 + 64];
            float a0 = 0.f, b0 = 0.f, a1 = 0.f, b1 = 0.f;
            #pragma unroll
            for (int kk = 0; kk < 16; ++kk) {
                float4 h0 = row0[kk];       // uniform address -> broadcast
                float4 h1 = row1[kk];
                a0 += h0.x*wl[4*kk] + h0.y*wl[4*kk+1] + h0.z*wl[4*kk+2] + h0.w*wl[4*kk+3];
                b0 += h0.x*wr[4*kk] + h0.y*wr[4*kk+1] + h0.z*wr[4*kk+2] + h0.w*wr[4*kk+3];
                a1 += h1.x*wl[4*kk] + h1.y*wl[4*kk+1] + h1.z*wl[4*kk+2] + h1.w*wl[4*kk+3];
                b1 += h1.x*wr[4*kk] + h1.y*wr[4*kk+1] + h1.z*wr[4*kk+2] + h1.w*wr[4*kk+3];
            }
            int rA = r0 + rr, rB = rA + 1;
            if (rA < n) { xl[(size_t)rA * D + lane] = a0; xr[(size_t)rA * D + lane] = b0; }
            if (rB < n) { xl[(size_t)rB * D + lane] = a1; xr[(size_t)rB * D + lane] = b1; }
        }
        // stage next group (data has arrived during compute)
        if (rn < n) {
            BN_ELU_APPLY(p0, p1)
            ((float4*)lp)[0] = p0; ((float4*)lp)[1] = p1;
        }
    }
}

// ---------------- fused GATv2 ----------------
// wave = contiguous, edge-balanced node range (wbeg); 16-lane group g = edge slot
// (4 edges/pack); lane owns 4 features. eas is pre-sorted edge_attr (CSR order).
// No online max (logits bounded; ratio identical to max-subtracted form).
// R12: We moves LDS -> REGISTERS (we[16] float4, loaded once per wave).
// DS-pipe arithmetic: 16 ds_read_b128/pack x ~210k packs x 12cyc / 256 CU
// ~= 62us of serialized DS time per dispatch — the R11 DPP win (-9.5us for
// removing just 4 lighter DS ops/pack) confirms the DS-bound model. Cost:
// VGPR ~80+64 -> 3 waves/SIMD (grid 768 co-resident). The TLP halving is
// acceptable BECAUSE the stall source it was hiding is removed, not kept.
// __launch_bounds__(256,2): cap 256 far above ~150 need -> no R2-style spill.
// DPP row reduce kept (R11 win). ea/srcs/X prefetch kept (R6: load-bearing).

template <int CTRL>
__device__ __forceinline__ float dpp_row_add(float x) {
    int yi = __builtin_amdgcn_update_dpp(0, __float_as_int(x), CTRL, 0xF, 0xF, true);
    return x + __int_as_float(yi);
}
__device__ __forceinline__ float row16_reduce(float x) {
    x = dpp_row_add<0xB1>(x);    // quad_perm [1,0,3,2]  (xor 1)
    x = dpp_row_add<0x4E>(x);    // quad_perm [2,3,0,1]  (xor 2)
    x = dpp_row_add<0x124>(x);   // row_ror:4  (adjacent quad partial)
    x = dpp_row_add<0x128>(x);   // row_ror:8  (full row sum, all lanes)
    return x;
}

#define EEV(c) (e0.x*we[0].c + e0.y*we[1].c + e0.z*we[2].c + e0.w*we[3].c \
              + e1.x*we[4].c + e1.y*we[5].c + e1.z*we[6].c + e1.w*we[7].c \
              + e2.x*we[8].c + e2.y*we[9].c + e2.z*we[10].c + e2.w*we[11].c \
              + e3.x*we[12].c + e3.y*we[13].c + e3.z*we[14].c + e3.w*we[15].c)

__global__ __launch_bounds__(256, 2) void k_gat(
        const float4* __restrict__ xl4, const float4* __restrict__ xr4,
        const float4* __restrict__ eas4, const int* __restrict__ srcs,
        const int* __restrict__ off, const int* __restrict__ wbeg,
        const float4* __restrict__ We4, const float4* __restrict__ att4,
        const float4* __restrict__ bias4, float* __restrict__ out,
        float* __restrict__ stat, int n, int do_elu) {
    __shared__ float ls[128];
    if (threadIdx.x < 128) ls[threadIdx.x] = 0.f;
    __syncthreads();
    int lane = threadIdx.x & 63;
    int g = lane >> 4, c16 = lane & 15;
    float4 we[ED];                          // We column block in REGISTERS (64 VGPR)
    #pragma unroll
    for (int j = 0; j < ED; ++j) we[j] = We4[j * 16 + c16];
    float4 av = att4[c16];
    float4 b4 = bias4[c16];
    int wid = blockIdx.x * (blockDim.x >> 6) + (threadIdx.x >> 6);
    int ns = wbeg[wid], nt = wbeg[wid + 1];
    float bsx = 0.f, bsy = 0.f, bsz = 0.f, bsw = 0.f;
    float bqx = 0.f, bqy = 0.f, bqz = 0.f, bqw = 0.f;
    int beg = (ns < nt) ? off[ns] : 0;
    for (int i = ns; i < nt; ++i) {
        int end = off[i + 1];
        int deg = end - beg;
        float4 xrv = xr4[i * 16 + c16];
        float denom = 0.f;
        float ax = 0.f, ay = 0.f, az = 0.f, aw = 0.f;
        float ex = 0.f, ey = 0.f, ez = 0.f, ew = 0.f;
        if (deg > 0) {
            // prologue: pack @ beg (srcs + ea + X all prefetched one iteration ahead)
            int actc = (g < deg);
            int p = beg + (actc ? g : 0);
            int s0 = srcs[p];
            int q = 4 * p;
            float4 e0 = eas4[q], e1 = eas4[q + 1], e2 = eas4[q + 2], e3 = eas4[q + 3];
            float4 X = xl4[s0 * 16 + c16];
            for (int pos = beg; pos < end; pos += 4) {
                int posn = pos + 4;
                int remn = end - posn;
                int actn = (remn > 0) && (g < remn);
                int pn = (remn > 0) ? posn + (actn ? g : 0) : pos;
                int sn = srcs[pn];                      // issue next srcs
                int qn = 4 * pn;                        // issue next ea (independent)
                float4 ne0 = eas4[qn],     ne1 = eas4[qn + 1];
                float4 ne2 = eas4[qn + 2], ne3 = eas4[qn + 3];
                // eev for current pack from REGISTER we (no DS ops)
                float eex = EEV(x), eey = EEV(y), eez = EEV(z), eew = EEV(w);
                // next xl gather (sn arrived during eev)
                float4 xn = xl4[sn * 16 + c16];
                float mk = actc ? 1.f : 0.f;
                ex += mk * eex; ey += mk * eey; ez += mk * eez; ew += mk * eew;
                float mx = X.x + xrv.x + eex;
                float my = X.y + xrv.y + eey;
                float mz = X.z + xrv.z + eez;
                float mw = X.w + xrv.w + eew;
                float p0 = fmaxf(mx, NEG * mx) * av.x
                         + fmaxf(my, NEG * my) * av.y
                         + fmaxf(mz, NEG * mz) * av.z
                         + fmaxf(mw, NEG * mw) * av.w;
                p0 = row16_reduce(p0);                  // DPP: VALU-pipe row sum
                float ev = mk * __expf(p0);
                denom += ev;
                ax += ev * X.x;
                ay += ev * X.y;
                az += ev * X.z;
                aw += ev * X.w;
                e0 = ne0; e1 = ne1; e2 = ne2; e3 = ne3; X = xn; actc = actn;
            }
        }
        // merge 4 per-group partials (plain sums — no max bookkeeping)
        #pragma unroll
        for (int o = 16; o <= 32; o <<= 1) {
            denom += __shfl_xor(denom, o, 64);
            ax += __shfl_xor(ax, o, 64);
            ay += __shfl_xor(ay, o, 64);
            az += __shfl_xor(az, o, 64);
            aw += __shfl_xor(aw, o, 64);
            ex += __shfl_xor(ex, o, 64);
            ey += __shfl_xor(ey, o, 64);
            ez += __shfl_xor(ez, o, 64);
            ew += __shfl_xor(ew, o, 64);
        }
        // self-loop (loop_attr@We == mean of incoming eev; 0 if deg==0)
        float inv = (deg > 0) ? 1.f / (float)deg : 0.f;
        float4 xli = xl4[i * 16 + c16];
        float mx = xli.x + xrv.x + ex * inv;
        float my = xli.y + xrv.y + ey * inv;
        float mz = xli.z + xrv.z + ez * inv;
        float mw = xli.w + xrv.w + ew * inv;
        float p0 = fmaxf(mx, NEG * mx) * av.x
                 + fmaxf(my, NEG * my) * av.y
                 + fmaxf(mz, NEG * mz) * av.z
                 + fmaxf(mw, NEG * mw) * av.w;
        p0 = row16_reduce(p0);                          // DPP row sum
        float ev = __expf(p0);
        denom += ev;
        ax += ev * xli.x;
        ay += ev * xli.y;
        az += ev * xli.z;
        aw += ev * xli.w;
        float invd = 1.f / denom;
        float ox = ax * invd + b4.x;
        float oy = ay * invd + b4.y;
        float oz = az * invd + b4.z;
        float ow = aw * invd + b4.w;
        if (do_elu) {
            ox = (ox > 0.f) ? ox : expm1f(ox);
            oy = (oy > 0.f) ? oy : expm1f(oy);
            oz = (oz > 0.f) ? oz : expm1f(oz);
            ow = (ow > 0.f) ? ow : expm1f(ow);
        }
        if (g == 0) {
            float4 o4; o4.x = ox; o4.y = oy; o4.z = oz; o4.w = ow;
            ((float4*)out)[i * 16 + c16] = o4;
            if (stat) {
                bsx += ox; bsy += oy; bsz += oz; bsw += ow;
                bqx += ox * ox; bqy += oy * oy; bqz += oz * oz; bqw += ow * ow;
            }
        }
        beg = end;
    }
    if (stat) {
        if (g == 0) {
            atomicAdd(&ls[c16 * 4 + 0], bsx);
            atomicAdd(&ls[c16 * 4 + 1], bsy);
            atomicAdd(&ls[c16 * 4 + 2], bsz);
            atomicAdd(&ls[c16 * 4 + 3], bsw);
            atomicAdd(&ls[64 + c16 * 4 + 0], bqx);
            atomicAdd(&ls[64 + c16 * 4 + 1], bqy);
            atomicAdd(&ls[64 + c16 * 4 + 2], bqz);
            atomicAdd(&ls[64 + c16 * 4 + 3], bqw);
        }
        __syncthreads();
        if (threadIdx.x < 128) atomicAdd(&stat[threadIdx.x], ls[threadIdx.x]);
    }
}

// ---------------- launch ----------------

extern "C" void kernel_launch(void* const* d_in, const int* in_sizes, int n_in,
                              void* d_out, int out_size, void* d_ws, size_t ws_size,
                              hipStream_t stream) {
    const float* x     = (const float*)d_in[0];
    const int*   ei    = (const int*)d_in[1];
    const float* ea    = (const float*)d_in[2];
    const float* Wl    = (const float*)d_in[3];
    const float* Wr    = (const float*)d_in[4];
    const float* We    = (const float*)d_in[5];
    const float* att   = (const float*)d_in[6];
    const float* bias  = (const float*)d_in[7];
    const float* gamma = (const float*)d_in[8];
    const float* beta  = (const float*)d_in[9];
    float* out = (float*)d_out;

    int n = in_sizes[0] / D;
    int e = in_sizes[1] / 2;
    const int* src = ei;
    const int* dst = ei + e;
    int nb = (n + 1023) / 1024;

    float* xl   = (float*)d_ws;
    float* xr   = xl + (size_t)n * D;
    float* hbuf = xr + (size_t)n * D;
    float* stat = hbuf + (size_t)n * D;        // [2][128]: raw {sum,sq} per BN
    float* eas  = stat + 256;                   // [e][16] pre-sorted edge_attr
    int* cnt  = (int*)(eas + (size_t)e * ED);
    int* fill = cnt + n;                        // adjacent to cnt: one memset
    int* off  = fill + n;
    int* bsum = off + n + 1;
    int* srcs = bsum + 256;
    int* wbeg = srcs + e;                       // [nw+1] edge-balanced partition

    // STATIC grids (R7 lesson: no runtime queries in kernel_launch).
    // k_gat @ ~150 VGPR (we in regs) -> 3 waves/SIMD -> 3 blocks/CU: 768.
    const int gat_grid  = 768;
    const int nw = gat_grid * 4;                // waves in k_gat
    const int gemm_grid = 512;                  // 3-4 grid-stride iters/wave (R6 win)

    hipMemsetAsync(cnt, 0, (size_t)(2 * n) * sizeof(int), stream);
    k_count<<<(e + 255) / 256, 256, 0, stream>>>(dst, cnt, stat, e);
    k_scan1<<<nb, 1024, 0, stream>>>(cnt, off, bsum, n);
    k_scan3<<<(n + 255) / 256, 256, 0, stream>>>(off, bsum, n, nb);
    k_scatter<<<(e + 255) / 256, 256, 0, stream>>>(src, dst, off, fill, srcs,
                                                   (float4*)eas, (const float4*)ea, e,
                                                   wbeg, nw, n);

    // layer 0: conv -> ELU (in gat) -> BN0 stats (epilogue); BN0 apply folded into gemm1
    k_gemm<<<gemm_grid, 256, 0, stream>>>(x, Wl, Wr, xl, xr, stat, gamma, beta, 0, n);
    k_gat<<<gat_grid, 256, 0, stream>>>((const float4*)xl, (const float4*)xr,
                                        (const float4*)eas, srcs, off, wbeg,
                                        (const float4*)We, (const float4*)att,
                                        (const float4*)bias, hbuf, stat, n, 1);
    // layer 1: conv (BN0 folded) -> BN1 stats (epilogue); BN1+ELU folded into gemm2
    k_gemm<<<gemm_grid, 256, 0, stream>>>(hbuf, Wl + D * D, Wr + D * D, xl, xr,
                                          stat, gamma, beta, 1, n);
    k_gat<<<gat_grid, 256, 0, stream>>>((const float4*)xl, (const float4*)xr,
                                        (const float4*)eas, srcs, off, wbeg,
                                        (const float4*)(We + ED * D), (const float4*)(att + D),
                                        (const float4*)(bias + D), hbuf, stat + 128, n, 0);
    // layer 2: conv (BN1+ELU folded) -> out
    k_gemm<<<gemm_grid, 256, 0, stream>>>(hbuf, Wl + 2 * D * D, Wr + 2 * D * D, xl, xr,
                                          stat + 128, gamma + D, beta + D, 2, n);
    k_gat<<<gat_grid, 256, 0, stream>>>((const float4*)xl, (const float4*)xr,
                                        (const float4*)eas, srcs, off, wbeg,
                                        (const float4*)(We + 2 * ED * D), (const float4*)(att + 2 * D),
                                        (const float4*)(bias + 2 * D), out, (float*)nullptr, n, 0);
}